// Round 1
// baseline (303.972 us; speedup 1.0000x reference)
//
#include <hip/hip_runtime.h>
#include <hip/hip_bf16.h>
#include <cstdint>
#include <cstddef>

typedef __attribute__((ext_vector_type(8))) short short8;
typedef __attribute__((ext_vector_type(4))) float floatx4;

#define B_ 32
#define H_ 8
#define D_ 512
#define DH_ 64
#define SQ_ 512
#define SK_ 512
#define NEG_INF_ -1000000000.0f

__device__ __forceinline__ short f2bf(float f) {
  union { float f; uint32_t u; } x; x.f = f;
  uint32_t r = x.u + 0x7FFFu + ((x.u >> 16) & 1u);
  return (short)(r >> 16);
}
__device__ __forceinline__ float bf2f(short s) {
  union { uint32_t u; float f; } x; x.u = ((uint32_t)(uint16_t)s) << 16;
  return x.f;
}

// Detect mask element layout: int32 (flag=0) vs byte/bool (flag=1).
// int32 layout of 0/1 values => every byte at offset%4 != 0 is zero.
__global__ void detect_mask_kernel(const uint8_t* __restrict__ m, int* __restrict__ flag) {
  __shared__ int found;
  if (threadIdx.x == 0) found = 0;
  __syncthreads();
  int any = 0;
  for (int i = threadIdx.x; i < B_ * SK_; i += 256) {
    if ((i & 3) != 0 && m[i] != 0) any = 1;
  }
  if (any) atomicOr(&found, 1);
  __syncthreads();
  if (threadIdx.x == 0) *flag = found;
}

__global__ void convw_kernel(const float* __restrict__ W, short* __restrict__ Wb) {
  const int i = blockIdx.x * 256 + threadIdx.x;  // 65536 threads, one float4 each
  const float4 f = reinterpret_cast<const float4*>(W)[i];
  short4 s;
  s.x = f2bf(f.x); s.y = f2bf(f.y); s.z = f2bf(f.z); s.w = f2bf(f.w);
  reinterpret_cast<short4*>(Wb)[i] = s;
}

// One block per (b, h, 64 q-rows). 4 waves, each owns 16 q-rows.
// Flash-style online softmax over 8 k-tiles of 64 columns.
__global__ __launch_bounds__(256) void attn_kernel(
    const float* __restrict__ q, const float* __restrict__ k, const float* __restrict__ v,
    const uint8_t* __restrict__ mask8,
    const float* __restrict__ gamma, const float* __restrict__ beta,
    const float* __restrict__ m_qk, const float* __restrict__ s_qk,
    const float* __restrict__ m_v, const float* __restrict__ s_v,
    short* __restrict__ xT, const int* __restrict__ maskflag)
{
  __shared__ short qbuf[64][80];      // Q^T tile: qbuf[qq][d]  (bf16, pad->160B rows, 16B aligned)
  __shared__ short kbuf[64][80];      // K^T tile: kbuf[ki][d]
  __shared__ short pbuf[4][16][80];   // per-wave P tile: pbuf[w][qrow][kk]

  const int qt = blockIdx.x;          // 0..7
  const int h  = blockIdx.y;          // 0..7
  const int b  = blockIdx.z;          // 0..31
  const int q0 = qt * 64;
  const int tid = threadIdx.x;
  const int w   = tid >> 6;
  const int l   = tid & 63;
  const int l15 = l & 15;
  const int dbase = (l >> 4) * 8;

  const int mask_is_byte = *maskflag;

  const float g  = gamma[h], be = beta[h], mq = m_qk[h], sq = s_qk[h];
  const float a_h = g / (sq * 8.0f);            // folds 1/sqrt(64)
  const float c_h = be - mq * g / sq;

  // ---- stage Q^T tile (transpose f32 global -> bf16 LDS) ----
  {
    const float* qb = q + ((size_t)b * D_ + h * DH_) * (size_t)SQ_ + q0;
    int dd = tid >> 4;                 // 0..15
    const int qg = (tid & 15) * 4;
    for (int it = 0; it < 4; ++it, dd += 16) {
      const float4 f = *reinterpret_cast<const float4*>(qb + (size_t)dd * SQ_ + qg);
      qbuf[qg + 0][dd] = f2bf(f.x);
      qbuf[qg + 1][dd] = f2bf(f.y);
      qbuf[qg + 2][dd] = f2bf(f.z);
      qbuf[qg + 3][dd] = f2bf(f.w);
    }
  }
  __syncthreads();

  short8 afrag0, afrag1;               // Q fragments, reused for all k-tiles
  {
    const int qq = w * 16 + l15;
    afrag0 = *reinterpret_cast<const short8*>(&qbuf[qq][dbase]);
    afrag1 = *reinterpret_cast<const short8*>(&qbuf[qq][dbase + 32]);
  }

  const floatx4 zero4 = {0.0f, 0.0f, 0.0f, 0.0f};
  float mrow[4], lrow[4];
  floatx4 oacc[4];
  for (int r = 0; r < 4; ++r) { mrow[r] = -__builtin_inff(); lrow[r] = 0.0f; }
  for (int ns = 0; ns < 4; ++ns) oacc[ns] = zero4;

  const float* kb_g = k + ((size_t)b * D_ + h * DH_) * (size_t)SK_;
  const float* vb_g = v + ((size_t)b * D_ + h * DH_) * (size_t)SK_;

  for (int kt = 0; kt < 8; ++kt) {
    const int k0 = kt * 64;
    __syncthreads();                   // prior kbuf/pbuf consumers done
    // ---- stage K^T tile ----
    {
      int dd = tid >> 4;
      const int kg = (tid & 15) * 4;
      for (int it = 0; it < 4; ++it, dd += 16) {
        const float4 f = *reinterpret_cast<const float4*>(kb_g + (size_t)dd * SK_ + k0 + kg);
        kbuf[kg + 0][dd] = f2bf(f.x);
        kbuf[kg + 1][dd] = f2bf(f.y);
        kbuf[kg + 2][dd] = f2bf(f.z);
        kbuf[kg + 3][dd] = f2bf(f.w);
      }
    }
    __syncthreads();

    // ---- S = Q^T K  (16 q-rows x 64 k-cols per wave) ----
    floatx4 sacc[4];
    for (int ns = 0; ns < 4; ++ns) sacc[ns] = zero4;
    for (int ns = 0; ns < 4; ++ns) {
      const short8 b0 = *reinterpret_cast<const short8*>(&kbuf[ns * 16 + l15][dbase]);
      const short8 b1 = *reinterpret_cast<const short8*>(&kbuf[ns * 16 + l15][dbase + 32]);
      sacc[ns] = __builtin_amdgcn_mfma_f32_16x16x32_bf16(afrag0, b0, sacc[ns], 0, 0, 0);
      sacc[ns] = __builtin_amdgcn_mfma_f32_16x16x32_bf16(afrag1, b1, sacc[ns], 0, 0, 0);
    }

    // ---- affine + mask ----
    bool mk[4];
    for (int ns = 0; ns < 4; ++ns) {
      const int col = k0 + ns * 16 + l15;
      int mv;
      if (mask_is_byte) mv = mask8[(size_t)b * SK_ + col];
      else              mv = reinterpret_cast<const int*>(mask8)[(size_t)b * SK_ + col];
      mk[ns] = (mv != 0);
    }
    float svv[4][4];
    for (int ns = 0; ns < 4; ++ns)
      for (int r = 0; r < 4; ++r)
        svv[ns][r] = mk[ns] ? NEG_INF_ : sacc[ns][r] * a_h + c_h;

    // ---- online softmax update ----
    float pr[4][4];
    for (int r = 0; r < 4; ++r) {
      float t = fmaxf(fmaxf(svv[0][r], svv[1][r]), fmaxf(svv[2][r], svv[3][r]));
      for (int off = 1; off < 16; off <<= 1) t = fmaxf(t, __shfl_xor(t, off, 64));
      const float mnew = fmaxf(mrow[r], t);
      const float scale = __expf(mrow[r] - mnew);
      float s0 = 0.0f;
      for (int ns = 0; ns < 4; ++ns) {
        const float p = __expf(svv[ns][r] - mnew);
        pr[ns][r] = p; s0 += p;
      }
      for (int off = 1; off < 16; off <<= 1) s0 += __shfl_xor(s0, off, 64);
      lrow[r] = lrow[r] * scale + s0;
      mrow[r] = mnew;
      for (int ns = 0; ns < 4; ++ns) oacc[ns][r] *= scale;
    }

    // ---- write P (bf16) to per-wave LDS tile ----
    for (int ns = 0; ns < 4; ++ns)
      for (int r = 0; r < 4; ++r)
        pbuf[w][(l >> 4) * 4 + r][ns * 16 + l15] = f2bf(pr[ns][r]);
    __syncthreads();

    // ---- O += P * V^T ----
    const short8 pa0 = *reinterpret_cast<const short8*>(&pbuf[w][l15][dbase]);
    const short8 pa1 = *reinterpret_cast<const short8*>(&pbuf[w][l15][dbase + 32]);
    for (int ns = 0; ns < 4; ++ns) {
      const float* vp = vb_g + (size_t)(ns * 16 + l15) * SK_ + k0;
      float4 va = *reinterpret_cast<const float4*>(vp + dbase);
      float4 vb = *reinterpret_cast<const float4*>(vp + dbase + 4);
      const short8 bf0 = { f2bf(va.x), f2bf(va.y), f2bf(va.z), f2bf(va.w),
                           f2bf(vb.x), f2bf(vb.y), f2bf(vb.z), f2bf(vb.w) };
      oacc[ns] = __builtin_amdgcn_mfma_f32_16x16x32_bf16(pa0, bf0, oacc[ns], 0, 0, 0);
      va = *reinterpret_cast<const float4*>(vp + 32 + dbase);
      vb = *reinterpret_cast<const float4*>(vp + 32 + dbase + 4);
      const short8 bf1 = { f2bf(va.x), f2bf(va.y), f2bf(va.z), f2bf(va.w),
                           f2bf(vb.x), f2bf(vb.y), f2bf(vb.z), f2bf(vb.w) };
      oacc[ns] = __builtin_amdgcn_mfma_f32_16x16x32_bf16(pa1, bf1, oacc[ns], 0, 0, 0);
    }
  }

  // ---- epilogue: x = (q + attn - m_v)/s_v, store x^T bf16 [b][q][d] ----
  float invl[4];
  for (int r = 0; r < 4; ++r) invl[r] = 1.0f / lrow[r];

  for (int ns = 0; ns < 4; ++ns) {
    const int dglob = h * DH_ + ns * 16 + l15;
    const float mv  = m_v[dglob];
    const float isv = 1.0f / s_v[dglob];
    for (int r = 0; r < 4; ++r) {
      const int qq = w * 16 + (l >> 4) * 4 + r;
      const float qres = bf2f(qbuf[qq][ns * 16 + l15]);
      const float val  = (qres + oacc[ns][r] * invl[r] - mv) * isv;
      xT[((size_t)b * SQ_ + q0 + qq) * (size_t)D_ + dglob] = f2bf(val);
    }
  }
}

// out[b,o,qi] = silu(bias[o] + sum_d W[o,d] * xT[b,qi,d]) — NT GEMM, both contiguous in d.
__global__ __launch_bounds__(256) void proj_kernel(
    const short* __restrict__ Wb, const short* __restrict__ xT,
    const float* __restrict__ bias, float* __restrict__ out)
{
  const int qt0 = blockIdx.x * 64;
  const int o0  = blockIdx.y * 64;
  const int b   = blockIdx.z;
  const int w   = threadIdx.x >> 6;
  const int l   = threadIdx.x & 63;
  const int l15 = l & 15;
  const int dbase = (l >> 4) * 8;

  const floatx4 zero4 = {0.0f, 0.0f, 0.0f, 0.0f};
  floatx4 acc[4];
  for (int ns = 0; ns < 4; ++ns) acc[ns] = zero4;

  const short* wrow = Wb + (size_t)(o0 + w * 16 + l15) * D_;
  const short* xrow = xT + ((size_t)b * SQ_ + qt0) * (size_t)D_;

  for (int step = 0; step < 16; ++step) {
    const short8 a = *reinterpret_cast<const short8*>(wrow + step * 32 + dbase);
    for (int ns = 0; ns < 4; ++ns) {
      const short8 bf = *reinterpret_cast<const short8*>(
          xrow + (size_t)(ns * 16 + l15) * D_ + step * 32 + dbase);
      acc[ns] = __builtin_amdgcn_mfma_f32_16x16x32_bf16(a, bf, acc[ns], 0, 0, 0);
    }
  }

  for (int ns = 0; ns < 4; ++ns) {
    const int qi = qt0 + ns * 16 + l15;
    for (int r = 0; r < 4; ++r) {
      const int o = o0 + w * 16 + (l >> 4) * 4 + r;
      const float val = acc[ns][r] + bias[o];
      const float sig = 1.0f / (1.0f + __expf(-val));
      out[((size_t)b * D_ + o) * (size_t)SQ_ + qi] = val * sig;
    }
  }
}

extern "C" void kernel_launch(void* const* d_in, const int* in_sizes, int n_in,
                              void* d_out, int out_size, void* d_ws, size_t ws_size,
                              hipStream_t stream) {
  const float*   q     = (const float*)d_in[0];
  const float*   k     = (const float*)d_in[1];
  const float*   v     = (const float*)d_in[2];
  const uint8_t* mask  = (const uint8_t*)d_in[3];
  const float*   gamma = (const float*)d_in[4];
  const float*   beta  = (const float*)d_in[5];
  const float*   m_qk  = (const float*)d_in[6];
  const float*   s_qk  = (const float*)d_in[7];
  const float*   m_v   = (const float*)d_in[8];
  const float*   s_v   = (const float*)d_in[9];
  const float*   W     = (const float*)d_in[10];
  const float*   bias  = (const float*)d_in[11];
  float* out = (float*)d_out;

  char* ws  = (char*)d_ws;
  short* Wb = (short*)ws;                               // 512*512*2   = 524288 B
  short* xT = (short*)(ws + 524288);                    // 32*512*512*2 = 16777216 B
  int* flag = (int*)(ws + 524288 + 16777216);           // 4 B

  detect_mask_kernel<<<1, 256, 0, stream>>>(mask, flag);
  convw_kernel<<<256, 256, 0, stream>>>(W, Wb);
  attn_kernel<<<dim3(8, 8, 32), 256, 0, stream>>>(q, k, v, mask, gamma, beta,
                                                  m_qk, s_qk, m_v, s_v, xT, flag);
  proj_kernel<<<dim3(8, 8, 32), 256, 0, stream>>>(Wb, xT, bias, out);
}

// Round 2
// 253.731 us; speedup vs baseline: 1.1980x; 1.1980x over previous
//
#include <hip/hip_runtime.h>
#include <hip/hip_bf16.h>
#include <cstdint>
#include <cstddef>

typedef __attribute__((ext_vector_type(8))) short short8;
typedef __attribute__((ext_vector_type(4))) float floatx4;

#define B_ 32
#define H_ 8
#define D_ 512
#define DH_ 64
#define SQ_ 512
#define SK_ 512
#define NEG_INF_ -1000000000.0f

__device__ __forceinline__ short f2bf(float f) {
  union { float f; uint32_t u; } x; x.f = f;
  uint32_t r = x.u + 0x7FFFu + ((x.u >> 16) & 1u);
  return (short)(r >> 16);
}
__device__ __forceinline__ float bf2f(short s) {
  union { uint32_t u; float f; } x; x.u = ((uint32_t)(uint16_t)s) << 16;
  return x.f;
}

// Detect mask element layout: int32 (flag=0) vs byte/bool (flag=1).
__global__ void detect_mask_kernel(const uint8_t* __restrict__ m, int* __restrict__ flag) {
  __shared__ int found;
  if (threadIdx.x == 0) found = 0;
  __syncthreads();
  int any = 0;
  for (int i = threadIdx.x; i < B_ * SK_; i += 256) {
    if ((i & 3) != 0 && m[i] != 0) any = 1;
  }
  if (any) atomicOr(&found, 1);
  __syncthreads();
  if (threadIdx.x == 0) *flag = found;
}

__global__ void convw_kernel(const float* __restrict__ W, short* __restrict__ Wb) {
  const int i = blockIdx.x * 256 + threadIdx.x;
  const float4 f = reinterpret_cast<const float4*>(W)[i];
  short4 s;
  s.x = f2bf(f.x); s.y = f2bf(f.y); s.z = f2bf(f.z); s.w = f2bf(f.w);
  reinterpret_cast<short4*>(Wb)[i] = s;
}

// v [B][D][S] f32 -> vb same layout bf16.  grid 8192 x 256, one float4/thread.
__global__ void convv_kernel(const float* __restrict__ v, short* __restrict__ vb) {
  const int i = blockIdx.x * 256 + threadIdx.x;
  const float4 f = reinterpret_cast<const float4*>(v)[i];
  short4 s;
  s.x = f2bf(f.x); s.y = f2bf(f.y); s.z = f2bf(f.z); s.w = f2bf(f.w);
  reinterpret_cast<short4*>(vb)[i] = s;
}

// msv[d] = (1/s_v[d], m_v[d]/s_v[d])
__global__ void msv_kernel(const float* __restrict__ m_v, const float* __restrict__ s_v,
                           float2* __restrict__ msv) {
  const int d = blockIdx.x * 256 + threadIdx.x;
  if (d < D_) {
    const float inv = 1.0f / s_v[d];
    msv[d] = make_float2(inv, m_v[d] * inv);
  }
}

// src f32 [B][D][S] -> dst bf16 [B][H][S][64] (per-head transpose+convert).
// grid (S/64, H, B), 256 threads.
__global__ __launch_bounds__(256) void transpose_kernel(const float* __restrict__ src,
                                                        short* __restrict__ dst) {
  __shared__ short t[64][68];
  const int s0 = blockIdx.x * 64, h = blockIdx.y, b = blockIdx.z;
  const int tid = threadIdx.x;
  const float* sp = src + ((size_t)b * D_ + h * DH_) * (size_t)SK_ + s0;
  const int sg = (tid & 15) * 4;
  int dloc = tid >> 4;
  for (int it = 0; it < 4; ++it, dloc += 16) {
    const float4 f = *reinterpret_cast<const float4*>(sp + (size_t)dloc * SK_ + sg);
    t[sg + 0][dloc] = f2bf(f.x);
    t[sg + 1][dloc] = f2bf(f.y);
    t[sg + 2][dloc] = f2bf(f.z);
    t[sg + 3][dloc] = f2bf(f.w);
  }
  __syncthreads();
  short* dp = dst + ((size_t)(b * H_ + h) * SQ_ + s0) * 64;
  for (int it = 0; it < 4; ++it) {
    const int c = tid + 256 * it;
    const int ss = c >> 4, pos = (c & 15) * 4;
    *reinterpret_cast<short4*>(dp + (size_t)ss * 64 + pos) =
        *reinterpret_cast<const short4*>(&t[ss][pos]);
  }
}

// One block per (b, h, 64 q-rows); 4 waves, wave w owns q-rows [w*16, w*16+16).
// All operands direct-from-global bf16; only per-wave pbuf in LDS; no barriers.
// Writes x = (q + attn - m_v)/s_v in place over qT (block owns its rows).
__global__ __launch_bounds__(256) void attn_kernel(
    short* __restrict__ xqT,            // [B][H][SQ][64] bf16: in qT, out x
    const short* __restrict__ kT,       // [B][H][SK][64] bf16
    const short* __restrict__ vb,       // [B][D][SK] bf16
    const uint8_t* __restrict__ mask8,
    const float* __restrict__ gamma, const float* __restrict__ beta,
    const float* __restrict__ m_qk, const float* __restrict__ s_qk,
    const float2* __restrict__ msv, const int* __restrict__ maskflag)
{
  __shared__ short pbuf[4][16][72];     // per-wave; stride 144B: 16B-aligned, 2-way max

  const int qt = blockIdx.x, h = blockIdx.y, b = blockIdx.z;
  const int q0 = qt * 64;
  const int tid = threadIdx.x, w = tid >> 6, l = tid & 63, l15 = l & 15;
  const int dbase = (l >> 4) * 8;
  const int mask_is_byte = *maskflag;

  const float g = gamma[h], be = beta[h], mq = m_qk[h], sq = s_qk[h];
  const float a_h = g / (sq * 8.0f);
  const float c_h = be - mq * g / sq;

  const size_t bh = (size_t)(b * H_ + h);
  short* qbase = xqT + (bh * SQ_ + q0) * 64;
  const short* kbase = kT + bh * SK_ * 64;
  const short* vbase = vb + ((size_t)b * D_ + h * DH_) * (size_t)SK_;

  const int qrow = w * 16 + l15;
  const short8 afrag0 = *reinterpret_cast<const short8*>(qbase + (size_t)qrow * 64 + dbase);
  const short8 afrag1 = *reinterpret_cast<const short8*>(qbase + (size_t)qrow * 64 + dbase + 32);

  const floatx4 zero4 = {0.0f, 0.0f, 0.0f, 0.0f};
  float mrow[4], lrow[4];
  floatx4 oacc[4];
  for (int r = 0; r < 4; ++r) { mrow[r] = -__builtin_inff(); lrow[r] = 0.0f; }
  for (int ns = 0; ns < 4; ++ns) oacc[ns] = zero4;

  for (int kt = 0; kt < 8; ++kt) {
    const int k0 = kt * 64;

    // ---- S = Q K^T ----
    floatx4 sacc[4];
    for (int ns = 0; ns < 4; ++ns) sacc[ns] = zero4;
    for (int ns = 0; ns < 4; ++ns) {
      const short* kr = kbase + (size_t)(k0 + ns * 16 + l15) * 64;
      const short8 b0 = *reinterpret_cast<const short8*>(kr + dbase);
      const short8 b1 = *reinterpret_cast<const short8*>(kr + dbase + 32);
      sacc[ns] = __builtin_amdgcn_mfma_f32_16x16x32_bf16(afrag0, b0, sacc[ns], 0, 0, 0);
      sacc[ns] = __builtin_amdgcn_mfma_f32_16x16x32_bf16(afrag1, b1, sacc[ns], 0, 0, 0);
    }

    // ---- affine + mask ----
    float svv[4][4];
    for (int ns = 0; ns < 4; ++ns) {
      const int col = k0 + ns * 16 + l15;
      int mv;
      if (mask_is_byte) mv = mask8[(size_t)b * SK_ + col];
      else              mv = reinterpret_cast<const int*>(mask8)[(size_t)b * SK_ + col];
      const bool mk = (mv != 0);
      for (int r = 0; r < 4; ++r)
        svv[ns][r] = mk ? NEG_INF_ : sacc[ns][r] * a_h + c_h;
    }

    // ---- online softmax (per q-row: 16-lane group reduce) ----
    for (int r = 0; r < 4; ++r) {
      float t = fmaxf(fmaxf(svv[0][r], svv[1][r]), fmaxf(svv[2][r], svv[3][r]));
      for (int off = 1; off < 16; off <<= 1) t = fmaxf(t, __shfl_xor(t, off, 64));
      const float mnew = fmaxf(mrow[r], t);
      const float scale = __expf(mrow[r] - mnew);
      float s0 = 0.0f;
      for (int ns = 0; ns < 4; ++ns) {
        const float p = __expf(svv[ns][r] - mnew);
        svv[ns][r] = p; s0 += p;
      }
      for (int off = 1; off < 16; off <<= 1) s0 += __shfl_xor(s0, off, 64);
      lrow[r] = lrow[r] * scale + s0;
      mrow[r] = mnew;
      for (int ns = 0; ns < 4; ++ns) oacc[ns][r] *= scale;
    }

    // ---- P to per-wave LDS (wave-internal, no barrier needed) ----
    for (int ns = 0; ns < 4; ++ns)
      for (int r = 0; r < 4; ++r)
        pbuf[w][(l >> 4) * 4 + r][ns * 16 + l15] = f2bf(svv[ns][r]);
    const short8 pa0 = *reinterpret_cast<const short8*>(&pbuf[w][l15][dbase]);
    const short8 pa1 = *reinterpret_cast<const short8*>(&pbuf[w][l15][dbase + 32]);

    // ---- O += P V^T (V fragments direct from global bf16) ----
    for (int ns = 0; ns < 4; ++ns) {
      const short* vp = vbase + (size_t)(ns * 16 + l15) * SK_ + k0;
      const short8 v0 = *reinterpret_cast<const short8*>(vp + dbase);
      const short8 v1 = *reinterpret_cast<const short8*>(vp + 32 + dbase);
      oacc[ns] = __builtin_amdgcn_mfma_f32_16x16x32_bf16(pa0, v0, oacc[ns], 0, 0, 0);
      oacc[ns] = __builtin_amdgcn_mfma_f32_16x16x32_bf16(pa1, v1, oacc[ns], 0, 0, 0);
    }
  }

  // ---- epilogue: x = (q + attn)*inv_s - m_v*inv_s, in place over qT ----
  float invl[4];
  for (int r = 0; r < 4; ++r) invl[r] = 1.0f / lrow[r];
  for (int ns = 0; ns < 4; ++ns)
    for (int r = 0; r < 4; ++r)
      pbuf[w][(l >> 4) * 4 + r][ns * 16 + l15] = f2bf(oacc[ns][r] * invl[r]);

  short* xr = qbase + (size_t)qrow * 64;
  for (int half = 0; half < 2; ++half) {
    const int off = dbase + 32 * half;
    const short8 pa = *reinterpret_cast<const short8*>(&pbuf[w][l15][off]);
    const short8 q8 = *reinterpret_cast<const short8*>(xr + off);
    short8 xv;
    for (int j = 0; j < 8; ++j) {
      const float2 c = msv[h * DH_ + off + j];
      xv[j] = f2bf((bf2f(pa[j]) + bf2f(q8[j])) * c.x - c.y);
    }
    *reinterpret_cast<short8*>(xr + off) = xv;
  }
}

// out[b,o,qi] = silu(bias[o] + sum_d W[o,d] x[b,qi,d]); x layout [b][h][q][64].
__global__ __launch_bounds__(256) void proj_kernel(
    const short* __restrict__ Wb, const short* __restrict__ xT,
    const float* __restrict__ bias, float* __restrict__ out)
{
  const int qt0 = blockIdx.x * 64;
  const int o0  = blockIdx.y * 64;
  const int b   = blockIdx.z;
  const int w   = threadIdx.x >> 6;
  const int l   = threadIdx.x & 63;
  const int l15 = l & 15;
  const int dbase = (l >> 4) * 8;

  const floatx4 zero4 = {0.0f, 0.0f, 0.0f, 0.0f};
  floatx4 acc[4];
  for (int ns = 0; ns < 4; ++ns) acc[ns] = zero4;

  const short* wrow = Wb + (size_t)(o0 + w * 16 + l15) * D_;
  const short* xb = xT + (size_t)b * H_ * SQ_ * 64;

  for (int step = 0; step < 16; ++step) {
    const short8 a = *reinterpret_cast<const short8*>(wrow + step * 32 + dbase);
    const int hk = step >> 1;
    const int off = (step & 1) * 32 + dbase;
    const short* xr = xb + ((size_t)hk * SQ_ + qt0) * 64 + off;
    for (int ns = 0; ns < 4; ++ns) {
      const short8 bf = *reinterpret_cast<const short8*>(xr + (size_t)(ns * 16 + l15) * 64);
      acc[ns] = __builtin_amdgcn_mfma_f32_16x16x32_bf16(a, bf, acc[ns], 0, 0, 0);
    }
  }

  for (int ns = 0; ns < 4; ++ns) {
    const int qi = qt0 + ns * 16 + l15;
    for (int r = 0; r < 4; ++r) {
      const int o = o0 + w * 16 + (l >> 4) * 4 + r;
      const float val = acc[ns][r] + bias[o];
      const float sig = 1.0f / (1.0f + __expf(-val));
      out[((size_t)b * D_ + o) * (size_t)SQ_ + qi] = val * sig;
    }
  }
}

extern "C" void kernel_launch(void* const* d_in, const int* in_sizes, int n_in,
                              void* d_out, int out_size, void* d_ws, size_t ws_size,
                              hipStream_t stream) {
  const float*   q     = (const float*)d_in[0];
  const float*   k     = (const float*)d_in[1];
  const float*   v     = (const float*)d_in[2];
  const uint8_t* mask  = (const uint8_t*)d_in[3];
  const float*   gamma = (const float*)d_in[4];
  const float*   beta  = (const float*)d_in[5];
  const float*   m_qk  = (const float*)d_in[6];
  const float*   s_qk  = (const float*)d_in[7];
  const float*   m_v   = (const float*)d_in[8];
  const float*   s_v   = (const float*)d_in[9];
  const float*   W     = (const float*)d_in[10];
  const float*   bias  = (const float*)d_in[11];
  float* out = (float*)d_out;

  char* ws = (char*)d_ws;
  short*  Wb   = (short*)ws;                                   // 512 KB
  short*  xqT  = (short*)(ws + (1u << 19));                    // 16 MB (qT then x)
  short*  kTb  = (short*)(ws + (1u << 19) + (1u << 24));       // 16 MB
  short*  vbb  = (short*)(ws + (1u << 19) + 2u * (1u << 24));  // 16 MB
  float2* msv  = (float2*)(ws + (1u << 19) + 3u * (1u << 24)); // 4 KB
  int*    flag = (int*)(ws + (1u << 19) + 3u * (1u << 24) + 4096);

  detect_mask_kernel<<<1, 256, 0, stream>>>(mask, flag);
  msv_kernel<<<2, 256, 0, stream>>>(m_v, s_v, msv);
  convw_kernel<<<256, 256, 0, stream>>>(W, Wb);
  transpose_kernel<<<dim3(8, 8, 32), 256, 0, stream>>>(q, xqT);
  transpose_kernel<<<dim3(8, 8, 32), 256, 0, stream>>>(k, kTb);
  convv_kernel<<<8192, 256, 0, stream>>>(v, vbb);
  attn_kernel<<<dim3(8, 8, 32), 256, 0, stream>>>(xqT, kTb, vbb, mask, gamma, beta,
                                                  m_qk, s_qk, msv, flag);
  proj_kernel<<<dim3(8, 8, 32), 256, 0, stream>>>(Wb, xqT, bias, out);
}

// Round 3
// 213.602 us; speedup vs baseline: 1.4231x; 1.1879x over previous
//
#include <hip/hip_runtime.h>
#include <hip/hip_bf16.h>
#include <cstdint>
#include <cstddef>

typedef __attribute__((ext_vector_type(8))) short short8;
typedef __attribute__((ext_vector_type(4))) float floatx4;
typedef __attribute__((ext_vector_type(16))) float floatx16;

#define B_ 32
#define H_ 8
#define D_ 512
#define DH_ 64
#define SQ_ 512
#define SK_ 512
#define NEG_INF_ -1000000000.0f
#define LOG2E_ 1.4426950408889634f

__device__ __forceinline__ short f2bf(float f) {
  union { float f; uint32_t u; } x; x.f = f;
  uint32_t r = x.u + 0x7FFFu + ((x.u >> 16) & 1u);
  return (short)(r >> 16);
}
__device__ __forceinline__ float bf2f(short s) {
  union { uint32_t u; float f; } x; x.u = ((uint32_t)(uint16_t)s) << 16;
  return x.f;
}
__device__ __forceinline__ uint32_t cvt_pk_bf16(float lo, float hi) {
  uint32_t r;
  asm("v_cvt_pk_bf16_f32 %0, %1, %2" : "=v"(r) : "v"(lo), "v"(hi));
  return r;
}

// Detect mask element layout: int32 (flag=0) vs byte/bool (flag=1).
__global__ void detect_mask_kernel(const uint8_t* __restrict__ m, int* __restrict__ flag) {
  __shared__ int found;
  if (threadIdx.x == 0) found = 0;
  __syncthreads();
  int any = 0;
  for (int i = threadIdx.x; i < B_ * SK_; i += 256) {
    if ((i & 3) != 0 && m[i] != 0) any = 1;
  }
  if (any) atomicOr(&found, 1);
  __syncthreads();
  if (threadIdx.x == 0) *flag = found;
}

// kbias[b][k] = mask ? NEG_INF*log2e : 0   (additive, log2 domain)
__global__ void bias_kernel(const uint8_t* __restrict__ mask8, const int* __restrict__ flag,
                            float* __restrict__ kbias) {
  const int b = blockIdx.x, t = threadIdx.x;  // 512 threads
  int mv;
  if (*flag) mv = mask8[b * SK_ + t];
  else       mv = reinterpret_cast<const int*>(mask8)[b * SK_ + t];
  kbias[b * SK_ + t] = mv ? NEG_INF_ * LOG2E_ : 0.0f;
}

__global__ void convw_kernel(const float* __restrict__ W, short* __restrict__ Wb) {
  const int i = blockIdx.x * 256 + threadIdx.x;
  const float4 f = reinterpret_cast<const float4*>(W)[i];
  short4 s;
  s.x = f2bf(f.x); s.y = f2bf(f.y); s.z = f2bf(f.z); s.w = f2bf(f.w);
  reinterpret_cast<short4*>(Wb)[i] = s;
}

__global__ void convv_kernel(const float* __restrict__ v, short* __restrict__ vb) {
  const int i = blockIdx.x * 256 + threadIdx.x;
  const float4 f = reinterpret_cast<const float4*>(v)[i];
  short4 s;
  s.x = f2bf(f.x); s.y = f2bf(f.y); s.z = f2bf(f.z); s.w = f2bf(f.w);
  reinterpret_cast<short4*>(vb)[i] = s;
}

__global__ void msv_kernel(const float* __restrict__ m_v, const float* __restrict__ s_v,
                           float2* __restrict__ msv) {
  const int d = blockIdx.x * 256 + threadIdx.x;
  if (d < D_) {
    const float inv = 1.0f / s_v[d];
    msv[d] = make_float2(inv, m_v[d] * inv);
  }
}

// src f32 [B][D][S] -> dst bf16 [B][H][S][64]
__global__ __launch_bounds__(256) void transpose_kernel(const float* __restrict__ src,
                                                        short* __restrict__ dst) {
  __shared__ short t[64][68];
  const int s0 = blockIdx.x * 64, h = blockIdx.y, b = blockIdx.z;
  const int tid = threadIdx.x;
  const float* sp = src + ((size_t)b * D_ + h * DH_) * (size_t)SK_ + s0;
  const int sg = (tid & 15) * 4;
  int dloc = tid >> 4;
  for (int it = 0; it < 4; ++it, dloc += 16) {
    const float4 f = *reinterpret_cast<const float4*>(sp + (size_t)dloc * SK_ + sg);
    t[sg + 0][dloc] = f2bf(f.x);
    t[sg + 1][dloc] = f2bf(f.y);
    t[sg + 2][dloc] = f2bf(f.z);
    t[sg + 3][dloc] = f2bf(f.w);
  }
  __syncthreads();
  short* dp = dst + ((size_t)(b * H_ + h) * SQ_ + s0) * 64;
  for (int it = 0; it < 4; ++it) {
    const int c = tid + 256 * it;
    const int ss = c >> 4, pos = (c & 15) * 4;
    *reinterpret_cast<short4*>(dp + (size_t)ss * 64 + pos) =
        *reinterpret_cast<const short4*>(&t[ss][pos]);
  }
}

// Swapped-operand 32x32 flash attention. 1024 blocks (XCD-swizzled), 4 waves,
// each wave owns 32 q-rows. S^T = mfma(K,Q): lane = q-col, regs = k-rows.
// Softmax in-register + one shfl_xor(32); P -> PV B-frag via cvt_pk + swap.
__global__ __launch_bounds__(256) void attn_kernel(
    short* __restrict__ xqT,            // [B][H][SQ][64] bf16: in qT, out x
    const short* __restrict__ kT,       // [B][H][SK][64] bf16
    const short* __restrict__ vb,       // [B][D][SK] bf16
    const float* __restrict__ gamma, const float* __restrict__ beta,
    const float* __restrict__ m_qk, const float* __restrict__ s_qk,
    const float2* __restrict__ msv, const float* __restrict__ kbias)
{
  __shared__ float bias_s[SK_];

  // bijective XCD swizzle: the 4 q-tiles of one (b,h) land on one XCD
  const int bid = blockIdx.x;
  const int xcd = bid & 7, ixc = bid >> 3;
  const int grp = xcd * 32 + (ixc >> 2);   // (b,h) group 0..255
  const int qt  = ixc & 3;
  const int h = grp & 7, b = grp >> 3;

  const int tid = threadIdx.x, w = tid >> 6, l = tid & 63;
  const int l31 = l & 31, hi = l >> 5;

  if (tid < 128)
    reinterpret_cast<floatx4*>(bias_s)[tid] =
        reinterpret_cast<const floatx4*>(kbias + (size_t)b * SK_)[tid];
  __syncthreads();

  const float gh = gamma[h], be = beta[h], mq = m_qk[h], sq = s_qk[h];
  const float a2 = gh / (sq * 8.0f) * LOG2E_;
  const float c2 = (be - mq * gh / sq) * LOG2E_;

  const size_t bh = (size_t)(b * H_ + h);
  short* qbase = xqT + (bh * SQ_ + qt * 128 + w * 32) * 64;
  const short* kbase = kT + bh * SK_ * 64;
  const short* vbase = vb + ((size_t)b * D_ + h * DH_) * (size_t)SK_;

  // Q fragments (B-operand): lane holds q=l31, d = st*16 + hi*8 + 0..7
  short8 qf[4];
  for (int st = 0; st < 4; ++st)
    qf[st] = *reinterpret_cast<const short8*>(qbase + (size_t)l31 * 64 + st * 16 + hi * 8);

  floatx16 oacc[2];
  for (int i = 0; i < 16; ++i) { oacc[0][i] = 0.f; oacc[1][i] = 0.f; }
  float mrow = -3.0e38f, lrow = 0.f;

  for (int it = 0; it < 8; ++it) {
    const int k0 = it * 64;

    floatx16 s0, s1;
    for (int i = 0; i < 16; ++i) { s0[i] = 0.f; s1[i] = 0.f; }
    __builtin_amdgcn_s_setprio(1);
    for (int st = 0; st < 4; ++st) {
      const short8 ka = *reinterpret_cast<const short8*>(
          kbase + (size_t)(k0 + l31) * 64 + st * 16 + hi * 8);
      s0 = __builtin_amdgcn_mfma_f32_32x32x16_bf16(ka, qf[st], s0, 0, 0, 0);
    }
    for (int st = 0; st < 4; ++st) {
      const short8 kb = *reinterpret_cast<const short8*>(
          kbase + (size_t)(k0 + 32 + l31) * 64 + st * 16 + hi * 8);
      s1 = __builtin_amdgcn_mfma_f32_32x32x16_bf16(kb, qf[st], s1, 0, 0, 0);
    }
    __builtin_amdgcn_s_setprio(0);

    // affine + mask-bias (log2 domain); reg r of sub -> k = sub*32 + (r&3)+8*(r>>2)+4*hi
    float sv[32];
    for (int sub = 0; sub < 2; ++sub)
      for (int gg = 0; gg < 4; ++gg) {
        const floatx4 bv = *reinterpret_cast<const floatx4*>(
            &bias_s[k0 + sub * 32 + gg * 8 + hi * 4]);
        for (int r = 0; r < 4; ++r) {
          const float sc = sub ? s1[gg * 4 + r] : s0[gg * 4 + r];
          sv[sub * 16 + gg * 4 + r] = sc * a2 + c2 + bv[r];
        }
      }

    // tile max: in-register tree + one cross-half shuffle
    float m16[16];
    for (int i = 0; i < 16; ++i) m16[i] = fmaxf(sv[i], sv[i + 16]);
    float m8[8];
    for (int i = 0; i < 8; ++i) m8[i] = fmaxf(m16[i], m16[i + 8]);
    float ma = fmaxf(fmaxf(m8[0], m8[4]), fmaxf(m8[1], m8[5]));
    float mb = fmaxf(fmaxf(m8[2], m8[6]), fmaxf(m8[3], m8[7]));
    float tm = fmaxf(ma, mb);
    tm = fmaxf(tm, __shfl_xor(tm, 32, 64));

    // defer-max rescale (T13)
    if (!__all(tm <= mrow + 6.0f)) {
      const float mnew = fmaxf(mrow, tm);
      const float scale = exp2f(mrow - mnew);
      lrow *= scale;
      for (int i = 0; i < 16; ++i) { oacc[0][i] *= scale; oacc[1][i] *= scale; }
      mrow = mnew;
    }

    float p[32];
    for (int i = 0; i < 32; ++i) p[i] = exp2f(sv[i] - mrow);
    float a16[16];
    for (int i = 0; i < 16; ++i) a16[i] = p[i] + p[i + 16];
    float a8[8];
    for (int i = 0; i < 8; ++i) a8[i] = a16[i] + a16[i + 8];
    float sa = (a8[0] + a8[4]) + (a8[1] + a8[5]);
    float sb = (a8[2] + a8[6]) + (a8[3] + a8[7]);
    float lsum = sa + sb;
    lsum += __shfl_xor(lsum, 32, 64);
    lrow += lsum;

    // P -> bf16 words; word j holds (k=2j, k=2j+1) of this lane's k-set
    uint32_t Wd[16], Rd[16];
    for (int j = 0; j < 16; ++j) Wd[j] = cvt_pk_bf16(p[2 * j], p[2 * j + 1]);
    for (int j = 0; j < 16; ++j) Rd[j] = (uint32_t)__shfl_xor((int)Wd[j], 32, 64);

    // PV: O^T[d][q] += V[d][k] * P[k][q], 4 k-chunks x 2 d-tiles
    __builtin_amdgcn_s_setprio(1);
    for (int kc = 0; kc < 4; ++kc) {
      const int base = (kc >> 1) * 8 + (kc & 1) * 4;
      union { uint32_t u[4]; short8 s; } pk;
      pk.u[0] = hi ? Rd[base + 2] : Wd[base + 0];
      pk.u[1] = hi ? Rd[base + 3] : Wd[base + 1];
      pk.u[2] = hi ? Wd[base + 2] : Rd[base + 0];
      pk.u[3] = hi ? Wd[base + 3] : Rd[base + 1];
      const short8 pb = pk.s;
      for (int dt = 0; dt < 2; ++dt) {
        const short8 va = *reinterpret_cast<const short8*>(
            vbase + (size_t)(dt * 32 + l31) * SK_ + k0 + kc * 16 + hi * 8);
        oacc[dt] = __builtin_amdgcn_mfma_f32_32x32x16_bf16(va, pb, oacc[dt], 0, 0, 0);
      }
    }
    __builtin_amdgcn_s_setprio(0);
  }

  // epilogue: x = (q + O/l)*inv_s - m*inv_s, in place over qT
  const float invl = 1.0f / lrow;
  short* xr = qbase + (size_t)l31 * 64;
  const float2* msvh = msv + h * DH_;
  for (int dt = 0; dt < 2; ++dt)
    for (int gg = 0; gg < 4; ++gg) {
      const int d0 = dt * 32 + gg * 8 + hi * 4;
      const short4 q4 = *reinterpret_cast<const short4*>(xr + d0);
      const float2 c0 = msvh[d0 + 0], c1 = msvh[d0 + 1],
                   c2v = msvh[d0 + 2], c3 = msvh[d0 + 3];
      short4 xv;
      xv.x = f2bf((bf2f(q4.x) + oacc[dt][gg * 4 + 0] * invl) * c0.x - c0.y);
      xv.y = f2bf((bf2f(q4.y) + oacc[dt][gg * 4 + 1] * invl) * c1.x - c1.y);
      xv.z = f2bf((bf2f(q4.z) + oacc[dt][gg * 4 + 2] * invl) * c2v.x - c2v.y);
      xv.w = f2bf((bf2f(q4.w) + oacc[dt][gg * 4 + 3] * invl) * c3.x - c3.y);
      *reinterpret_cast<short4*>(xr + d0) = xv;
    }
}

// out[b,o,qi] = silu(bias[o] + sum_d W[o,d] x[b,qi,d]); x layout [b][h][q][64].
__global__ __launch_bounds__(256) void proj_kernel(
    const short* __restrict__ Wb, const short* __restrict__ xT,
    const float* __restrict__ bias, float* __restrict__ out)
{
  const int qt0 = blockIdx.x * 64;
  const int o0  = blockIdx.y * 64;
  const int b   = blockIdx.z;
  const int w   = threadIdx.x >> 6;
  const int l   = threadIdx.x & 63;
  const int l15 = l & 15;
  const int dbase = (l >> 4) * 8;

  const floatx4 zero4 = {0.0f, 0.0f, 0.0f, 0.0f};
  floatx4 acc[4];
  for (int ns = 0; ns < 4; ++ns) acc[ns] = zero4;

  const short* wrow = Wb + (size_t)(o0 + w * 16 + l15) * D_;
  const short* xb = xT + (size_t)b * H_ * SQ_ * 64;

  for (int step = 0; step < 16; ++step) {
    const short8 a = *reinterpret_cast<const short8*>(wrow + step * 32 + dbase);
    const int hk = step >> 1;
    const int off = (step & 1) * 32 + dbase;
    const short* xr = xb + ((size_t)hk * SQ_ + qt0) * 64 + off;
    for (int ns = 0; ns < 4; ++ns) {
      const short8 bf = *reinterpret_cast<const short8*>(xr + (size_t)(ns * 16 + l15) * 64);
      acc[ns] = __builtin_amdgcn_mfma_f32_16x16x32_bf16(a, bf, acc[ns], 0, 0, 0);
    }
  }

  for (int ns = 0; ns < 4; ++ns) {
    const int qi = qt0 + ns * 16 + l15;
    for (int r = 0; r < 4; ++r) {
      const int o = o0 + w * 16 + (l >> 4) * 4 + r;
      const float val = acc[ns][r] + bias[o];
      const float sig = 1.0f / (1.0f + __expf(-val));
      out[((size_t)b * D_ + o) * (size_t)SQ_ + qi] = val * sig;
    }
  }
}

extern "C" void kernel_launch(void* const* d_in, const int* in_sizes, int n_in,
                              void* d_out, int out_size, void* d_ws, size_t ws_size,
                              hipStream_t stream) {
  const float*   q     = (const float*)d_in[0];
  const float*   k     = (const float*)d_in[1];
  const float*   v     = (const float*)d_in[2];
  const uint8_t* mask  = (const uint8_t*)d_in[3];
  const float*   gamma = (const float*)d_in[4];
  const float*   beta  = (const float*)d_in[5];
  const float*   m_qk  = (const float*)d_in[6];
  const float*   s_qk  = (const float*)d_in[7];
  const float*   m_v   = (const float*)d_in[8];
  const float*   s_v   = (const float*)d_in[9];
  const float*   W     = (const float*)d_in[10];
  const float*   bias  = (const float*)d_in[11];
  float* out = (float*)d_out;

  char* ws = (char*)d_ws;
  short*  Wb    = (short*)ws;                                   // 512 KB
  short*  xqT   = (short*)(ws + (1u << 19));                    // 16 MB
  short*  kTb   = (short*)(ws + (1u << 19) + (1u << 24));       // 16 MB
  short*  vbb   = (short*)(ws + (1u << 19) + 2u * (1u << 24));  // 16 MB
  float2* msv   = (float2*)(ws + (1u << 19) + 3u * (1u << 24)); // 4 KB
  int*    flag  = (int*)(ws + (1u << 19) + 3u * (1u << 24) + 4096);
  float*  kbias = (float*)(ws + (1u << 19) + 3u * (1u << 24) + 8192); // 64 KB

  detect_mask_kernel<<<1, 256, 0, stream>>>(mask, flag);
  bias_kernel<<<B_, 512, 0, stream>>>(mask, flag, kbias);
  msv_kernel<<<2, 256, 0, stream>>>(m_v, s_v, msv);
  convw_kernel<<<256, 256, 0, stream>>>(W, Wb);
  transpose_kernel<<<dim3(8, 8, 32), 256, 0, stream>>>(q, xqT);
  transpose_kernel<<<dim3(8, 8, 32), 256, 0, stream>>>(k, kTb);
  convv_kernel<<<8192, 256, 0, stream>>>(v, vbb);
  attn_kernel<<<1024, 256, 0, stream>>>(xqT, kTb, vbb, gamma, beta,
                                        m_qk, s_qk, msv, kbias);
  proj_kernel<<<dim3(8, 8, 32), 256, 0, stream>>>(Wb, xqT, bias, out);
}

// Round 4
// 156.141 us; speedup vs baseline: 1.9468x; 1.3680x over previous
//
#include <hip/hip_runtime.h>
#include <hip/hip_bf16.h>
#include <cstdint>
#include <cstddef>

typedef __attribute__((ext_vector_type(8))) short short8;
typedef __attribute__((ext_vector_type(4))) float floatx4;
typedef __attribute__((ext_vector_type(16))) float floatx16;

#define B_ 32
#define H_ 8
#define D_ 512
#define DH_ 64
#define SQ_ 512
#define SK_ 512
#define NEG_INF_ -1000000000.0f
#define LOG2E_ 1.4426950408889634f

__device__ __forceinline__ short f2bf(float f) {
  union { float f; uint32_t u; } x; x.f = f;
  uint32_t r = x.u + 0x7FFFu + ((x.u >> 16) & 1u);
  return (short)(r >> 16);
}
__device__ __forceinline__ float bf2f(short s) {
  union { uint32_t u; float f; } x; x.u = ((uint32_t)(uint16_t)s) << 16;
  return x.f;
}
__device__ __forceinline__ uint32_t cvt_pk_bf16(float lo, float hi) {
  uint32_t r;
  asm("v_cvt_pk_bf16_f32 %0, %1, %2" : "=v"(r) : "v"(lo), "v"(hi));
  return r;
}

// Detect mask element layout: int32 (flag=0) vs byte/bool (flag=1).
__global__ void detect_mask_kernel(const uint8_t* __restrict__ m, int* __restrict__ flag) {
  __shared__ int found;
  if (threadIdx.x == 0) found = 0;
  __syncthreads();
  int any = 0;
  for (int i = threadIdx.x; i < B_ * SK_; i += 256) {
    if ((i & 3) != 0 && m[i] != 0) any = 1;
  }
  if (any) atomicOr(&found, 1);
  __syncthreads();
  if (threadIdx.x == 0) *flag = found;
}

// kbias[b][k] = mask ? NEG_INF*log2e : 0   (additive, log2 domain)
__global__ void bias_kernel(const uint8_t* __restrict__ mask8, const int* __restrict__ flag,
                            float* __restrict__ kbias) {
  const int b = blockIdx.x, t = threadIdx.x;  // 512 threads
  int mv;
  if (*flag) mv = mask8[b * SK_ + t];
  else       mv = reinterpret_cast<const int*>(mask8)[b * SK_ + t];
  kbias[b * SK_ + t] = mv ? NEG_INF_ * LOG2E_ : 0.0f;
}

__global__ void convw_kernel(const float* __restrict__ W, short* __restrict__ Wb) {
  const int i = blockIdx.x * 256 + threadIdx.x;
  const float4 f = reinterpret_cast<const float4*>(W)[i];
  short4 s;
  s.x = f2bf(f.x); s.y = f2bf(f.y); s.z = f2bf(f.z); s.w = f2bf(f.w);
  reinterpret_cast<short4*>(Wb)[i] = s;
}

__global__ void convv_kernel(const float* __restrict__ v, short* __restrict__ vb) {
  const int i = blockIdx.x * 256 + threadIdx.x;
  const float4 f = reinterpret_cast<const float4*>(v)[i];
  short4 s;
  s.x = f2bf(f.x); s.y = f2bf(f.y); s.z = f2bf(f.z); s.w = f2bf(f.w);
  reinterpret_cast<short4*>(vb)[i] = s;
}

__global__ void msv_kernel(const float* __restrict__ m_v, const float* __restrict__ s_v,
                           float2* __restrict__ msv) {
  const int d = blockIdx.x * 256 + threadIdx.x;
  if (d < D_) {
    const float inv = 1.0f / s_v[d];
    msv[d] = make_float2(inv, m_v[d] * inv);
  }
}

// src f32 [B][D][S] -> dst bf16 [B][H][S][64]
__global__ __launch_bounds__(256) void transpose_kernel(const float* __restrict__ src,
                                                        short* __restrict__ dst) {
  __shared__ short t[64][68];
  const int s0 = blockIdx.x * 64, h = blockIdx.y, b = blockIdx.z;
  const int tid = threadIdx.x;
  const float* sp = src + ((size_t)b * D_ + h * DH_) * (size_t)SK_ + s0;
  const int sg = (tid & 15) * 4;
  int dloc = tid >> 4;
  for (int it = 0; it < 4; ++it, dloc += 16) {
    const float4 f = *reinterpret_cast<const float4*>(sp + (size_t)dloc * SK_ + sg);
    t[sg + 0][dloc] = f2bf(f.x);
    t[sg + 1][dloc] = f2bf(f.y);
    t[sg + 2][dloc] = f2bf(f.z);
    t[sg + 3][dloc] = f2bf(f.w);
  }
  __syncthreads();
  short* dp = dst + ((size_t)(b * H_ + h) * SQ_ + s0) * 64;
  for (int it = 0; it < 4; ++it) {
    const int c = tid + 256 * it;
    const int ss = c >> 4, pos = (c & 15) * 4;
    *reinterpret_cast<short4*>(dp + (size_t)ss * 64 + pos) =
        *reinterpret_cast<const short4*>(&t[ss][pos]);
  }
}

// Swapped-operand 32x32 flash attention. 1024 blocks (XCD-swizzled), 4 waves,
// each wave owns 32 q-rows. S^T = mfma(K,Q): lane = q-col, regs = k-rows.
// Per-wave k-phase rotation decorrelates memory phases (softmax k-order-invariant).
__global__ __launch_bounds__(256) void attn_kernel(
    short* __restrict__ xqT,            // [B][H][SQ][64] bf16: in qT, out x
    const short* __restrict__ kT,       // [B][H][SK][64] bf16
    const short* __restrict__ vb,       // [B][D][SK] bf16
    const float* __restrict__ gamma, const float* __restrict__ beta,
    const float* __restrict__ m_qk, const float* __restrict__ s_qk,
    const float2* __restrict__ msv, const float* __restrict__ kbias)
{
  __shared__ float bias_s[SK_];

  // bijective XCD swizzle: the 4 q-tiles of one (b,h) land on one XCD
  const int bid = blockIdx.x;
  const int xcd = bid & 7, ixc = bid >> 3;
  const int grp = xcd * 32 + (ixc >> 2);   // (b,h) group 0..255
  const int qt  = ixc & 3;
  const int h = grp & 7, b = grp >> 3;

  const int tid = threadIdx.x, w = tid >> 6, l = tid & 63;
  const int l31 = l & 31, hi = l >> 5;

  const float gh = gamma[h], be = beta[h], mq = m_qk[h], sq = s_qk[h];
  const float a2 = gh / (sq * 8.0f) * LOG2E_;
  const float c2 = (be - mq * gh / sq) * LOG2E_;

  if (tid < 128) {
    floatx4 t = reinterpret_cast<const floatx4*>(kbias + (size_t)b * SK_)[tid];
    t += c2;                             // fold affine offset into the bias row
    reinterpret_cast<floatx4*>(bias_s)[tid] = t;
  }
  __syncthreads();

  const size_t bh = (size_t)(b * H_ + h);
  short* qbase = xqT + (bh * SQ_ + qt * 128 + w * 32) * 64;
  const short* kbase = kT + bh * SK_ * 64;
  const short* vbase = vb + ((size_t)b * D_ + h * DH_) * (size_t)SK_;

  // Q fragments (B-operand): lane holds q=l31, d = st*16 + hi*8 + 0..7
  short8 qf[4];
  for (int st = 0; st < 4; ++st)
    qf[st] = *reinterpret_cast<const short8*>(qbase + (size_t)l31 * 64 + st * 16 + hi * 8);

  floatx16 oacc[2];
  for (int i = 0; i < 16; ++i) { oacc[0][i] = 0.f; oacc[1][i] = 0.f; }
  float mrow = -3.0e38f, lrow = 0.f;

  const int phase = (w << 1) | (qt & 1);

  for (int it = 0; it < 8; ++it) {
    const int k0 = ((it + phase) & 7) * 64;

    floatx16 s0, s1;
    for (int i = 0; i < 16; ++i) { s0[i] = 0.f; s1[i] = 0.f; }
    __builtin_amdgcn_s_setprio(1);
    for (int st = 0; st < 4; ++st) {
      const short8 ka = *reinterpret_cast<const short8*>(
          kbase + (size_t)(k0 + l31) * 64 + st * 16 + hi * 8);
      s0 = __builtin_amdgcn_mfma_f32_32x32x16_bf16(ka, qf[st], s0, 0, 0, 0);
    }
    for (int st = 0; st < 4; ++st) {
      const short8 kb = *reinterpret_cast<const short8*>(
          kbase + (size_t)(k0 + 32 + l31) * 64 + st * 16 + hi * 8);
      s1 = __builtin_amdgcn_mfma_f32_32x32x16_bf16(kb, qf[st], s1, 0, 0, 0);
    }
    __builtin_amdgcn_s_setprio(0);

    // hoist first V-pair: overlaps its latency with the softmax VALU work
    const short8 v00 = *reinterpret_cast<const short8*>(
        vbase + (size_t)l31 * SK_ + k0 + hi * 8);
    const short8 v01 = *reinterpret_cast<const short8*>(
        vbase + (size_t)(32 + l31) * SK_ + k0 + hi * 8);

    // affine + mask-bias (log2 domain); reg r of sub -> k = sub*32+8*gg+4*hi+r
    float sv[32];
    for (int sub = 0; sub < 2; ++sub)
      for (int gg = 0; gg < 4; ++gg) {
        const floatx4 bv = *reinterpret_cast<const floatx4*>(
            &bias_s[k0 + sub * 32 + gg * 8 + hi * 4]);
        for (int r = 0; r < 4; ++r) {
          const float sc = sub ? s1[gg * 4 + r] : s0[gg * 4 + r];
          sv[sub * 16 + gg * 4 + r] = __builtin_fmaf(sc, a2, bv[r]);
        }
      }

    // tile max: in-register tree + one cross-half shuffle
    float m16[16];
    for (int i = 0; i < 16; ++i) m16[i] = fmaxf(sv[i], sv[i + 16]);
    float m8[8];
    for (int i = 0; i < 8; ++i) m8[i] = fmaxf(m16[i], m16[i + 8]);
    float ma = fmaxf(fmaxf(m8[0], m8[4]), fmaxf(m8[1], m8[5]));
    float mb = fmaxf(fmaxf(m8[2], m8[6]), fmaxf(m8[3], m8[7]));
    float tm = fmaxf(ma, mb);
    tm = fmaxf(tm, __shfl_xor(tm, 32, 64));

    // defer-max rescale (T13)
    if (!__all(tm <= mrow + 6.0f)) {
      const float mnew = fmaxf(mrow, tm);
      const float scale = exp2f(mrow - mnew);
      lrow *= scale;
      for (int i = 0; i < 16; ++i) { oacc[0][i] *= scale; oacc[1][i] *= scale; }
      mrow = mnew;
    }

    float p[32];
    for (int i = 0; i < 32; ++i) p[i] = exp2f(sv[i] - mrow);
    float a16[16];
    for (int i = 0; i < 16; ++i) a16[i] = p[i] + p[i + 16];
    float a8[8];
    for (int i = 0; i < 8; ++i) a8[i] = a16[i] + a16[i + 8];
    float sa = (a8[0] + a8[4]) + (a8[1] + a8[5]);
    float sb = (a8[2] + a8[6]) + (a8[3] + a8[7]);
    float lsum = sa + sb;
    lsum += __shfl_xor(lsum, 32, 64);
    lrow += lsum;

    // P -> bf16 words; word j holds (k=2j, k=2j+1) of this lane's k-set
    uint32_t Wd[16], Rd[16];
    for (int j = 0; j < 16; ++j) Wd[j] = cvt_pk_bf16(p[2 * j], p[2 * j + 1]);
    for (int j = 0; j < 16; ++j) Rd[j] = (uint32_t)__shfl_xor((int)Wd[j], 32, 64);

    // PV: O^T[d][q] += V[d][k] * P[k][q], 4 k-chunks x 2 d-tiles
    __builtin_amdgcn_s_setprio(1);
    for (int kc = 0; kc < 4; ++kc) {
      const int base = (kc >> 1) * 8 + (kc & 1) * 4;
      union { uint32_t u[4]; short8 s; } pk;
      pk.u[0] = hi ? Rd[base + 2] : Wd[base + 0];
      pk.u[1] = hi ? Rd[base + 3] : Wd[base + 1];
      pk.u[2] = hi ? Wd[base + 2] : Rd[base + 0];
      pk.u[3] = hi ? Wd[base + 3] : Rd[base + 1];
      const short8 pb = pk.s;
      short8 va0, va1;
      if (kc == 0) { va0 = v00; va1 = v01; }
      else {
        va0 = *reinterpret_cast<const short8*>(
            vbase + (size_t)l31 * SK_ + k0 + kc * 16 + hi * 8);
        va1 = *reinterpret_cast<const short8*>(
            vbase + (size_t)(32 + l31) * SK_ + k0 + kc * 16 + hi * 8);
      }
      oacc[0] = __builtin_amdgcn_mfma_f32_32x32x16_bf16(va0, pb, oacc[0], 0, 0, 0);
      oacc[1] = __builtin_amdgcn_mfma_f32_32x32x16_bf16(va1, pb, oacc[1], 0, 0, 0);
    }
    __builtin_amdgcn_s_setprio(0);
  }

  // epilogue: x = (q + O/l)*inv_s - m*inv_s, in place over qT
  const float invl = 1.0f / lrow;
  short* xr = qbase + (size_t)l31 * 64;
  const float2* msvh = msv + h * DH_;
  for (int dt = 0; dt < 2; ++dt)
    for (int gg = 0; gg < 4; ++gg) {
      const int d0 = dt * 32 + gg * 8 + hi * 4;
      const short4 q4 = *reinterpret_cast<const short4*>(xr + d0);
      const float2 c0 = msvh[d0 + 0], c1 = msvh[d0 + 1],
                   c2v = msvh[d0 + 2], c3 = msvh[d0 + 3];
      short4 xv;
      xv.x = f2bf((bf2f(q4.x) + oacc[dt][gg * 4 + 0] * invl) * c0.x - c0.y);
      xv.y = f2bf((bf2f(q4.y) + oacc[dt][gg * 4 + 1] * invl) * c1.x - c1.y);
      xv.z = f2bf((bf2f(q4.z) + oacc[dt][gg * 4 + 2] * invl) * c2v.x - c2v.y);
      xv.w = f2bf((bf2f(q4.w) + oacc[dt][gg * 4 + 3] * invl) * c3.x - c3.y);
      *reinterpret_cast<short4*>(xr + d0) = xv;
    }
}

// proj: out[b,o,q] = silu(bias[o] + sum_d W[o,d] x[b,q,d]); x layout [b][h][q][64].
// Block = 256 o x 64 q; 4 waves each 64x64. x-tile (64 KB) staged once in LDS,
// XOR-swizzled (c16 ^= row&7) to kill stride-1KB bank aliasing; W from global (L2).
__global__ __launch_bounds__(256) void proj_kernel(
    const short* __restrict__ Wb, const short* __restrict__ xT,
    const float* __restrict__ bias, float* __restrict__ out)
{
  __shared__ short xs[64 * 512];        // [row=q][c16=16B unit, swizzled], 64 KB
  const int q0 = blockIdx.x * 64;       // 8
  const int o0 = blockIdx.y * 256;      // 2
  const int b  = blockIdx.z;            // 32
  const int tid = threadIdx.x, w = tid >> 6, l = tid & 63;
  const int l15 = l & 15, g = l >> 4;

  // ---- stage x tile: wave w stages h-planes 2w, 2w+1 (contiguous 8 KB each) ----
  const short* xb = xT + (size_t)b * (H_ * SQ_ * 64);
  for (int hh = w * 2; hh < w * 2 + 2; ++hh) {
    const short* src = xb + ((size_t)hh * SQ_ + q0) * 64;
    for (int j = 0; j < 8; ++j) {
      const short8 val = *reinterpret_cast<const short8*>(src + j * 512 + l * 8);
      const int row = j * 8 + (l >> 3);
      const int c16 = (hh * 8 + (l & 7)) ^ (row & 7);
      *reinterpret_cast<short8*>(&xs[row * 512 + c16 * 8]) = val;
    }
  }
  __syncthreads();

  floatx4 acc[4][4];
  for (int ai = 0; ai < 4; ++ai)
    for (int bj = 0; bj < 4; ++bj)
      acc[ai][bj] = floatx4{0.f, 0.f, 0.f, 0.f};

  const short* wbase = Wb + (size_t)(o0 + w * 64 + l15) * D_;

  for (int step = 0; step < 16; ++step) {
    short8 af[4];
    for (int ai = 0; ai < 4; ++ai)
      af[ai] = *reinterpret_cast<const short8*>(
          wbase + (size_t)(ai * 16) * D_ + step * 32 + g * 8);
    short8 bf[4];
    for (int bj = 0; bj < 4; ++bj) {
      const int row = bj * 16 + l15;
      const int c16 = (step * 4 + g) ^ (row & 7);
      bf[bj] = *reinterpret_cast<const short8*>(&xs[row * 512 + c16 * 8]);
    }
    for (int ai = 0; ai < 4; ++ai)
      for (int bj = 0; bj < 4; ++bj)
        acc[ai][bj] = __builtin_amdgcn_mfma_f32_16x16x32_bf16(af[ai], bf[bj],
                                                              acc[ai][bj], 0, 0, 0);
  }

  for (int ai = 0; ai < 4; ++ai)
    for (int r = 0; r < 4; ++r) {
      const int o = o0 + w * 64 + ai * 16 + g * 4 + r;
      const float bo = bias[o];
      float* orow = out + ((size_t)b * D_ + o) * SQ_ + q0;
      for (int bj = 0; bj < 4; ++bj) {
        const float val = acc[ai][bj][r] + bo;
        orow[bj * 16 + l15] = val * (1.0f / (1.0f + __expf(-val)));
      }
    }
}

extern "C" void kernel_launch(void* const* d_in, const int* in_sizes, int n_in,
                              void* d_out, int out_size, void* d_ws, size_t ws_size,
                              hipStream_t stream) {
  const float*   q     = (const float*)d_in[0];
  const float*   k     = (const float*)d_in[1];
  const float*   v     = (const float*)d_in[2];
  const uint8_t* mask  = (const uint8_t*)d_in[3];
  const float*   gamma = (const float*)d_in[4];
  const float*   beta  = (const float*)d_in[5];
  const float*   m_qk  = (const float*)d_in[6];
  const float*   s_qk  = (const float*)d_in[7];
  const float*   m_v   = (const float*)d_in[8];
  const float*   s_v   = (const float*)d_in[9];
  const float*   W     = (const float*)d_in[10];
  const float*   bias  = (const float*)d_in[11];
  float* out = (float*)d_out;

  char* ws = (char*)d_ws;
  short*  Wb    = (short*)ws;                                   // 512 KB
  short*  xqT   = (short*)(ws + (1u << 19));                    // 16 MB
  short*  kTb   = (short*)(ws + (1u << 19) + (1u << 24));       // 16 MB
  short*  vbb   = (short*)(ws + (1u << 19) + 2u * (1u << 24));  // 16 MB
  float2* msv   = (float2*)(ws + (1u << 19) + 3u * (1u << 24)); // 4 KB
  int*    flag  = (int*)(ws + (1u << 19) + 3u * (1u << 24) + 4096);
  float*  kbias = (float*)(ws + (1u << 19) + 3u * (1u << 24) + 8192); // 64 KB

  detect_mask_kernel<<<1, 256, 0, stream>>>(mask, flag);
  bias_kernel<<<B_, 512, 0, stream>>>(mask, flag, kbias);
  msv_kernel<<<2, 256, 0, stream>>>(m_v, s_v, msv);
  convw_kernel<<<256, 256, 0, stream>>>(W, Wb);
  transpose_kernel<<<dim3(8, 8, 32), 256, 0, stream>>>(q, xqT);
  transpose_kernel<<<dim3(8, 8, 32), 256, 0, stream>>>(k, kTb);
  convv_kernel<<<8192, 256, 0, stream>>>(v, vbb);
  attn_kernel<<<1024, 256, 0, stream>>>(xqT, kTb, vbb, gamma, beta,
                                        m_qk, s_qk, msv, kbias);
  proj_kernel<<<dim3(8, 2, 32), 256, 0, stream>>>(Wb, xqT, bias, out);
}

// Round 5
// 155.122 us; speedup vs baseline: 1.9596x; 1.0066x over previous
//
#include <hip/hip_runtime.h>
#include <hip/hip_bf16.h>
#include <cstdint>
#include <cstddef>

typedef __attribute__((ext_vector_type(8))) short short8;
typedef __attribute__((ext_vector_type(4))) float floatx4;
typedef __attribute__((ext_vector_type(16))) float floatx16;

#define B_ 32
#define H_ 8
#define D_ 512
#define DH_ 64
#define SQ_ 512
#define SK_ 512
#define NEG_INF_ -1000000000.0f
#define LOG2E_ 1.4426950408889634f
#define FIXED_MAX_ 24.0f

__device__ __forceinline__ short f2bf(float f) {
  union { float f; uint32_t u; } x; x.f = f;
  uint32_t r = x.u + 0x7FFFu + ((x.u >> 16) & 1u);
  return (short)(r >> 16);
}
__device__ __forceinline__ float bf2f(short s) {
  union { uint32_t u; float f; } x; x.u = ((uint32_t)(uint16_t)s) << 16;
  return x.f;
}
__device__ __forceinline__ uint32_t cvt_pk_bf16(float lo, float hi) {
  uint32_t r;
  asm("v_cvt_pk_bf16_f32 %0, %1, %2" : "=v"(r) : "v"(lo), "v"(hi));
  return r;
}
// Swap upper-half lanes of a with lower-half lanes of b (both modified).
__device__ __forceinline__ void plane32_swap(uint32_t& a, uint32_t& b) {
  asm("v_permlane32_swap_b32 %0, %1" : "+v"(a), "+v"(b));
}

// Detect mask element layout: int32 (flag=0) vs byte/bool (flag=1).
__global__ void detect_mask_kernel(const uint8_t* __restrict__ m, int* __restrict__ flag) {
  __shared__ int found;
  if (threadIdx.x == 0) found = 0;
  __syncthreads();
  int any = 0;
  for (int i = threadIdx.x; i < B_ * SK_; i += 256) {
    if ((i & 3) != 0 && m[i] != 0) any = 1;
  }
  if (any) atomicOr(&found, 1);
  __syncthreads();
  if (threadIdx.x == 0) *flag = found;
}

// kbias[b][k] = mask ? NEG_INF*log2e : 0   (additive, log2 domain)
__global__ void bias_kernel(const uint8_t* __restrict__ mask8, const int* __restrict__ flag,
                            float* __restrict__ kbias) {
  const int b = blockIdx.x, t = threadIdx.x;  // 512 threads
  int mv;
  if (*flag) mv = mask8[b * SK_ + t];
  else       mv = reinterpret_cast<const int*>(mask8)[b * SK_ + t];
  kbias[b * SK_ + t] = mv ? NEG_INF_ * LOG2E_ : 0.0f;
}

__global__ void convw_kernel(const float* __restrict__ W, short* __restrict__ Wb) {
  const int i = blockIdx.x * 256 + threadIdx.x;
  const float4 f = reinterpret_cast<const float4*>(W)[i];
  short4 s;
  s.x = f2bf(f.x); s.y = f2bf(f.y); s.z = f2bf(f.z); s.w = f2bf(f.w);
  reinterpret_cast<short4*>(Wb)[i] = s;
}

__global__ void convv_kernel(const float* __restrict__ v, short* __restrict__ vb) {
  const int i = blockIdx.x * 256 + threadIdx.x;
  const float4 f = reinterpret_cast<const float4*>(v)[i];
  short4 s;
  s.x = f2bf(f.x); s.y = f2bf(f.y); s.z = f2bf(f.z); s.w = f2bf(f.w);
  reinterpret_cast<short4*>(vb)[i] = s;
}

__global__ void msv_kernel(const float* __restrict__ m_v, const float* __restrict__ s_v,
                           float2* __restrict__ msv) {
  const int d = blockIdx.x * 256 + threadIdx.x;
  if (d < D_) {
    const float inv = 1.0f / s_v[d];
    msv[d] = make_float2(inv, m_v[d] * inv);
  }
}

// fused q+k transpose: src f32 [B][D][S] -> dst bf16 [B][H][S][64]; z = b*2 + (0=q,1=k)
__global__ __launch_bounds__(256) void transpose2_kernel(
    const float* __restrict__ qs, const float* __restrict__ ks,
    short* __restrict__ qd, short* __restrict__ kd) {
  __shared__ short t[64][68];
  const int s0 = blockIdx.x * 64, h = blockIdx.y, z = blockIdx.z;
  const int b = z >> 1;
  const float* src = (z & 1) ? ks : qs;
  short* dst = (z & 1) ? kd : qd;
  const int tid = threadIdx.x;
  const float* sp = src + ((size_t)b * D_ + h * DH_) * (size_t)SK_ + s0;
  const int sg = (tid & 15) * 4;
  int dloc = tid >> 4;
  for (int it = 0; it < 4; ++it, dloc += 16) {
    const float4 f = *reinterpret_cast<const float4*>(sp + (size_t)dloc * SK_ + sg);
    t[sg + 0][dloc] = f2bf(f.x);
    t[sg + 1][dloc] = f2bf(f.y);
    t[sg + 2][dloc] = f2bf(f.z);
    t[sg + 3][dloc] = f2bf(f.w);
  }
  __syncthreads();
  short* dp = dst + ((size_t)(b * H_ + h) * SQ_ + s0) * 64;
  for (int it = 0; it < 4; ++it) {
    const int c = tid + 256 * it;
    const int ss = c >> 4, pos = (c & 15) * 4;
    *reinterpret_cast<short4*>(dp + (size_t)ss * 64 + pos) =
        *reinterpret_cast<const short4*>(&t[ss][pos]);
  }
}

// Swapped-operand 32x32 flash attention, fixed-max softmax (P = exp2(s-24)),
// 8 waves/block split-k: wave (pid, half) does q-rows pid*32.., k in half*256..+256.
// Partials merged via one LDS exchange (pure add — no rescale needed).
__global__ __launch_bounds__(512) void attn_kernel(
    short* __restrict__ xqT,            // [B][H][SQ][64] bf16: in qT, out x
    const short* __restrict__ kT,       // [B][H][SK][64] bf16
    const short* __restrict__ vb,       // [B][D][SK] bf16
    const float* __restrict__ gamma, const float* __restrict__ beta,
    const float* __restrict__ m_qk, const float* __restrict__ s_qk,
    const float2* __restrict__ msv, const float* __restrict__ kbias)
{
  __shared__ float bias_s[SK_];
  __shared__ float Opart[4][32][68];    // row 272 B = 17*16B: float4s spread banks
  __shared__ float Lpart[4][32];

  // bijective XCD swizzle: the 4 q-tiles of one (b,h) land on one XCD
  const int bid = blockIdx.x;
  const int xcd = bid & 7, ixc = bid >> 3;
  const int grp = xcd * 32 + (ixc >> 2);   // (b,h) group 0..255
  const int qt  = ixc & 3;
  const int h = grp & 7, b = grp >> 3;

  const int tid = threadIdx.x, w = tid >> 6, l = tid & 63;
  const int pid = w & 3, half = w >> 2;
  const int l31 = l & 31, hi = l >> 5;

  const float gh = gamma[h], be = beta[h], mq = m_qk[h], sq = s_qk[h];
  const float a2 = gh / (sq * 8.0f) * LOG2E_;
  const float c2 = (be - mq * gh / sq) * LOG2E_ - FIXED_MAX_;

  if (tid < 128) {
    floatx4 t = reinterpret_cast<const floatx4*>(kbias + (size_t)b * SK_)[tid];
    t += c2;                             // fold affine offset + fixed max
    reinterpret_cast<floatx4*>(bias_s)[tid] = t;
  }
  __syncthreads();

  const size_t bh = (size_t)(b * H_ + h);
  short* qbase = xqT + (bh * SQ_ + qt * 128 + pid * 32) * 64;
  const short* kbase = kT + bh * SK_ * 64;
  const short* vbase = vb + ((size_t)b * D_ + h * DH_) * (size_t)SK_;

  // Q fragments (B-operand): lane holds q=l31, d = st*16 + hi*8 + 0..7
  short8 qf[4];
  for (int st = 0; st < 4; ++st)
    qf[st] = *reinterpret_cast<const short8*>(qbase + (size_t)l31 * 64 + st * 16 + hi * 8);

  floatx16 oacc[2];
  for (int i = 0; i < 16; ++i) { oacc[0][i] = 0.f; oacc[1][i] = 0.f; }
  float lpart = 0.f;

  for (int it = 0; it < 4; ++it) {
    const int k0 = half * 256 + ((it + pid) & 3) * 64;  // per-wave k-phase rotation

    floatx16 s0, s1;
    for (int i = 0; i < 16; ++i) { s0[i] = 0.f; s1[i] = 0.f; }
    __builtin_amdgcn_s_setprio(1);
    for (int st = 0; st < 4; ++st) {
      const short8 ka = *reinterpret_cast<const short8*>(
          kbase + (size_t)(k0 + l31) * 64 + st * 16 + hi * 8);
      s0 = __builtin_amdgcn_mfma_f32_32x32x16_bf16(ka, qf[st], s0, 0, 0, 0);
    }
    for (int st = 0; st < 4; ++st) {
      const short8 kb = *reinterpret_cast<const short8*>(
          kbase + (size_t)(k0 + 32 + l31) * 64 + st * 16 + hi * 8);
      s1 = __builtin_amdgcn_mfma_f32_32x32x16_bf16(kb, qf[st], s1, 0, 0, 0);
    }
    __builtin_amdgcn_s_setprio(0);

    // hoist first V-pair: overlaps its latency with the exp2 VALU work
    const short8 v00 = *reinterpret_cast<const short8*>(
        vbase + (size_t)l31 * SK_ + k0 + hi * 8);
    const short8 v01 = *reinterpret_cast<const short8*>(
        vbase + (size_t)(32 + l31) * SK_ + k0 + hi * 8);

    // P = exp2(s*a2 + bias); reg r of sub -> k = sub*32 + 8*gg + 4*hi + r
    float p[32];
    for (int sub = 0; sub < 2; ++sub)
      for (int gg = 0; gg < 4; ++gg) {
        const floatx4 bv = *reinterpret_cast<const floatx4*>(
            &bias_s[k0 + sub * 32 + gg * 8 + hi * 4]);
        for (int r = 0; r < 4; ++r) {
          const float sc = sub ? s1[gg * 4 + r] : s0[gg * 4 + r];
          p[sub * 16 + gg * 4 + r] = exp2f(__builtin_fmaf(sc, a2, bv[r]));
        }
      }

    // partial row-sum (lane-local only; cross-lane deferred to end)
    {
      float a16[16];
      for (int i = 0; i < 16; ++i) a16[i] = p[i] + p[i + 16];
      float a8[8];
      for (int i = 0; i < 8; ++i) a8[i] = a16[i] + a16[i + 8];
      lpart += ((a8[0] + a8[4]) + (a8[1] + a8[5])) + ((a8[2] + a8[6]) + (a8[3] + a8[7]));
    }

    // P -> bf16 words; word j holds (k=2j, k=2j+1) of this lane's k-set
    uint32_t Wd[16];
    for (int j = 0; j < 16; ++j) Wd[j] = cvt_pk_bf16(p[2 * j], p[2 * j + 1]);

    // PV: O^T[d][q] += V[d][k] * P[k][q]; cross-half P exchange via permlane32_swap
    __builtin_amdgcn_s_setprio(1);
    for (int kc = 0; kc < 4; ++kc) {
      const int base = (kc >> 1) * 8 + (kc & 1) * 4;
      uint32_t x0 = Wd[base + 0], x1 = Wd[base + 1];
      uint32_t y0 = Wd[base + 2], y1 = Wd[base + 3];
      plane32_swap(x0, y0);   // x0: own/partner-upper word0; y0: partner/own word2
      plane32_swap(x1, y1);
      union { uint32_t u[4]; short8 s; } pk;
      pk.u[0] = x0; pk.u[1] = x1; pk.u[2] = y0; pk.u[3] = y1;
      const short8 pb = pk.s;
      short8 va0, va1;
      if (kc == 0) { va0 = v00; va1 = v01; }
      else {
        va0 = *reinterpret_cast<const short8*>(
            vbase + (size_t)l31 * SK_ + k0 + kc * 16 + hi * 8);
        va1 = *reinterpret_cast<const short8*>(
            vbase + (size_t)(32 + l31) * SK_ + k0 + kc * 16 + hi * 8);
      }
      oacc[0] = __builtin_amdgcn_mfma_f32_32x32x16_bf16(va0, pb, oacc[0], 0, 0, 0);
      oacc[1] = __builtin_amdgcn_mfma_f32_32x32x16_bf16(va1, pb, oacc[1], 0, 0, 0);
    }
    __builtin_amdgcn_s_setprio(0);
  }

  lpart += __shfl_xor(lpart, 32, 64);   // complete this k-half's row sum

  // ---- split-k merge: half 0 publishes, half 1 combines + epilogue ----
  if (half == 0) {
    for (int dt = 0; dt < 2; ++dt)
      for (int gg = 0; gg < 4; ++gg) {
        floatx4 o4 = {oacc[dt][gg * 4 + 0], oacc[dt][gg * 4 + 1],
                      oacc[dt][gg * 4 + 2], oacc[dt][gg * 4 + 3]};
        *reinterpret_cast<floatx4*>(&Opart[pid][l31][dt * 32 + gg * 8 + hi * 4]) = o4;
      }
    if (hi == 0) Lpart[pid][l31] = lpart;
  }
  __syncthreads();
  if (half == 1) {
    const float lrow = lpart + Lpart[pid][l31];
    const float invl = 1.0f / lrow;
    short* xr = qbase + (size_t)l31 * 64;
    const float2* msvh = msv + h * DH_;
    for (int dt = 0; dt < 2; ++dt)
      for (int gg = 0; gg < 4; ++gg) {
        const int d0 = dt * 32 + gg * 8 + hi * 4;
        const floatx4 o4 = *reinterpret_cast<const floatx4*>(&Opart[pid][l31][d0]);
        const short4 q4 = *reinterpret_cast<const short4*>(xr + d0);
        const float2 c0 = msvh[d0 + 0], c1 = msvh[d0 + 1],
                     c2v = msvh[d0 + 2], c3 = msvh[d0 + 3];
        short4 xv;
        xv.x = f2bf((bf2f(q4.x) + (oacc[dt][gg * 4 + 0] + o4[0]) * invl) * c0.x - c0.y);
        xv.y = f2bf((bf2f(q4.y) + (oacc[dt][gg * 4 + 1] + o4[1]) * invl) * c1.x - c1.y);
        xv.z = f2bf((bf2f(q4.z) + (oacc[dt][gg * 4 + 2] + o4[2]) * invl) * c2v.x - c2v.y);
        xv.w = f2bf((bf2f(q4.w) + (oacc[dt][gg * 4 + 3] + o4[3]) * invl) * c3.x - c3.y);
        *reinterpret_cast<short4*>(xr + d0) = xv;
      }
  }
}

// proj: out[b,o,q] = silu(bias[o] + sum_d W[o,d] x[b,q,d]); x layout [b][h][q][64].
__global__ __launch_bounds__(256) void proj_kernel(
    const short* __restrict__ Wb, const short* __restrict__ xT,
    const float* __restrict__ bias, float* __restrict__ out)
{
  __shared__ short xs[64 * 512];        // [row=q][c16, swizzled], 64 KB
  const int q0 = blockIdx.x * 64;
  const int o0 = blockIdx.y * 256;
  const int b  = blockIdx.z;
  const int tid = threadIdx.x, w = tid >> 6, l = tid & 63;
  const int l15 = l & 15, g = l >> 4;

  const short* xb = xT + (size_t)b * (H_ * SQ_ * 64);
  for (int hh = w * 2; hh < w * 2 + 2; ++hh) {
    const short* src = xb + ((size_t)hh * SQ_ + q0) * 64;
    for (int j = 0; j < 8; ++j) {
      const short8 val = *reinterpret_cast<const short8*>(src + j * 512 + l * 8);
      const int row = j * 8 + (l >> 3);
      const int c16 = (hh * 8 + (l & 7)) ^ (row & 7);
      *reinterpret_cast<short8*>(&xs[row * 512 + c16 * 8]) = val;
    }
  }
  __syncthreads();

  floatx4 acc[4][4];
  for (int ai = 0; ai < 4; ++ai)
    for (int bj = 0; bj < 4; ++bj)
      acc[ai][bj] = floatx4{0.f, 0.f, 0.f, 0.f};

  const short* wbase = Wb + (size_t)(o0 + w * 64 + l15) * D_;

  for (int step = 0; step < 16; ++step) {
    short8 af[4];
    for (int ai = 0; ai < 4; ++ai)
      af[ai] = *reinterpret_cast<const short8*>(
          wbase + (size_t)(ai * 16) * D_ + step * 32 + g * 8);
    short8 bf[4];
    for (int bj = 0; bj < 4; ++bj) {
      const int row = bj * 16 + l15;
      const int c16 = (step * 4 + g) ^ (row & 7);
      bf[bj] = *reinterpret_cast<const short8*>(&xs[row * 512 + c16 * 8]);
    }
    for (int ai = 0; ai < 4; ++ai)
      for (int bj = 0; bj < 4; ++bj)
        acc[ai][bj] = __builtin_amdgcn_mfma_f32_16x16x32_bf16(af[ai], bf[bj],
                                                              acc[ai][bj], 0, 0, 0);
  }

  for (int ai = 0; ai < 4; ++ai)
    for (int r = 0; r < 4; ++r) {
      const int o = o0 + w * 64 + ai * 16 + g * 4 + r;
      const float bo = bias[o];
      float* orow = out + ((size_t)b * D_ + o) * SQ_ + q0;
      for (int bj = 0; bj < 4; ++bj) {
        const float val = acc[ai][bj][r] + bo;
        orow[bj * 16 + l15] = val * (1.0f / (1.0f + __expf(-val)));
      }
    }
}

extern "C" void kernel_launch(void* const* d_in, const int* in_sizes, int n_in,
                              void* d_out, int out_size, void* d_ws, size_t ws_size,
                              hipStream_t stream) {
  const float*   q     = (const float*)d_in[0];
  const float*   k     = (const float*)d_in[1];
  const float*   v     = (const float*)d_in[2];
  const uint8_t* mask  = (const uint8_t*)d_in[3];
  const float*   gamma = (const float*)d_in[4];
  const float*   beta  = (const float*)d_in[5];
  const float*   m_qk  = (const float*)d_in[6];
  const float*   s_qk  = (const float*)d_in[7];
  const float*   m_v   = (const float*)d_in[8];
  const float*   s_v   = (const float*)d_in[9];
  const float*   W     = (const float*)d_in[10];
  const float*   bias  = (const float*)d_in[11];
  float* out = (float*)d_out;

  char* ws = (char*)d_ws;
  short*  Wb    = (short*)ws;                                   // 512 KB
  short*  xqT   = (short*)(ws + (1u << 19));                    // 16 MB
  short*  kTb   = (short*)(ws + (1u << 19) + (1u << 24));       // 16 MB
  short*  vbb   = (short*)(ws + (1u << 19) + 2u * (1u << 24));  // 16 MB
  float2* msv   = (float2*)(ws + (1u << 19) + 3u * (1u << 24)); // 4 KB
  int*    flag  = (int*)(ws + (1u << 19) + 3u * (1u << 24) + 4096);
  float*  kbias = (float*)(ws + (1u << 19) + 3u * (1u << 24) + 8192); // 64 KB

  detect_mask_kernel<<<1, 256, 0, stream>>>(mask, flag);
  bias_kernel<<<B_, 512, 0, stream>>>(mask, flag, kbias);
  msv_kernel<<<2, 256, 0, stream>>>(m_v, s_v, msv);
  convw_kernel<<<256, 256, 0, stream>>>(W, Wb);
  transpose2_kernel<<<dim3(8, 8, 64), 256, 0, stream>>>(q, k, xqT, kTb);
  convv_kernel<<<8192, 256, 0, stream>>>(v, vbb);
  attn_kernel<<<1024, 512, 0, stream>>>(xqT, kTb, vbb, gamma, beta,
                                        m_qk, s_qk, msv, kbias);
  proj_kernel<<<dim3(8, 2, 32), 256, 0, stream>>>(Wb, xqT, bias, out);
}

// Round 6
// 124.760 us; speedup vs baseline: 2.4365x; 1.2434x over previous
//
#include <hip/hip_runtime.h>
#include <hip/hip_bf16.h>
#include <cstdint>
#include <cstddef>

typedef __attribute__((ext_vector_type(8))) short short8;
typedef __attribute__((ext_vector_type(4))) float floatx4;
typedef __attribute__((ext_vector_type(16))) float floatx16;

#define B_ 32
#define H_ 8
#define D_ 512
#define DH_ 64
#define SQ_ 512
#define SK_ 512
#define NEG_INF_ -1000000000.0f
#define LOG2E_ 1.4426950408889634f
#define FIXED_MAX_ 24.0f

__device__ __forceinline__ short f2bf(float f) {
  union { float f; uint32_t u; } x; x.f = f;
  uint32_t r = x.u + 0x7FFFu + ((x.u >> 16) & 1u);
  return (short)(r >> 16);
}
__device__ __forceinline__ float bf2f(short s) {
  union { uint32_t u; float f; } x; x.u = ((uint32_t)(uint16_t)s) << 16;
  return x.f;
}
__device__ __forceinline__ uint32_t cvt_pk_bf16(float lo, float hi) {
  uint32_t r;
  asm("v_cvt_pk_bf16_f32 %0, %1, %2" : "=v"(r) : "v"(lo), "v"(hi));
  return r;
}
// Swap upper-half lanes of a with lower-half lanes of b (both modified).
__device__ __forceinline__ void plane32_swap(uint32_t& a, uint32_t& b) {
  asm("v_permlane32_swap_b32 %0, %1" : "+v"(a), "+v"(b));
}
// Async global->LDS, 16B per lane. LDS dest = uniform base + lane*16 (linear);
// global src is per-lane (swizzle goes on the source side — G21/m173).
__device__ __forceinline__ void gload16(const void* g, void* lds) {
  __builtin_amdgcn_global_load_lds(
      (const __attribute__((address_space(1))) void*)g,
      (__attribute__((address_space(3))) void*)lds, 16, 0, 0);
}

// Detect mask element layout: int32 (flag=0) vs byte/bool (flag=1).
__global__ void detect_mask_kernel(const uint8_t* __restrict__ m, int* __restrict__ flag) {
  __shared__ int found;
  if (threadIdx.x == 0) found = 0;
  __syncthreads();
  int any = 0;
  for (int i = threadIdx.x; i < B_ * SK_; i += 256) {
    if ((i & 3) != 0 && m[i] != 0) any = 1;
  }
  if (any) atomicOr(&found, 1);
  __syncthreads();
  if (threadIdx.x == 0) *flag = found;
}

// kbias[b][k] = mask ? NEG_INF*log2e : 0   (additive, log2 domain)
__global__ void bias_kernel(const uint8_t* __restrict__ mask8, const int* __restrict__ flag,
                            float* __restrict__ kbias) {
  const int b = blockIdx.x, t = threadIdx.x;  // 512 threads
  int mv;
  if (*flag) mv = mask8[b * SK_ + t];
  else       mv = reinterpret_cast<const int*>(mask8)[b * SK_ + t];
  kbias[b * SK_ + t] = mv ? NEG_INF_ * LOG2E_ : 0.0f;
}

__global__ void convw_kernel(const float* __restrict__ W, short* __restrict__ Wb) {
  const int i = blockIdx.x * 256 + threadIdx.x;
  const float4 f = reinterpret_cast<const float4*>(W)[i];
  short4 s;
  s.x = f2bf(f.x); s.y = f2bf(f.y); s.z = f2bf(f.z); s.w = f2bf(f.w);
  reinterpret_cast<short4*>(Wb)[i] = s;
}

__global__ void convv_kernel(const float* __restrict__ v, short* __restrict__ vb) {
  const int i = blockIdx.x * 256 + threadIdx.x;
  const float4 f = reinterpret_cast<const float4*>(v)[i];
  short4 s;
  s.x = f2bf(f.x); s.y = f2bf(f.y); s.z = f2bf(f.z); s.w = f2bf(f.w);
  reinterpret_cast<short4*>(vb)[i] = s;
}

__global__ void msv_kernel(const float* __restrict__ m_v, const float* __restrict__ s_v,
                           float2* __restrict__ msv) {
  const int d = blockIdx.x * 256 + threadIdx.x;
  if (d < D_) {
    const float inv = 1.0f / s_v[d];
    msv[d] = make_float2(inv, m_v[d] * inv);
  }
}

// fused q+k transpose: src f32 [B][D][S] -> dst bf16 [B][H][S][64]; z = b*2 + (0=q,1=k)
__global__ __launch_bounds__(256) void transpose2_kernel(
    const float* __restrict__ qs, const float* __restrict__ ks,
    short* __restrict__ qd, short* __restrict__ kd) {
  __shared__ short t[64][68];
  const int s0 = blockIdx.x * 64, h = blockIdx.y, z = blockIdx.z;
  const int b = z >> 1;
  const float* src = (z & 1) ? ks : qs;
  short* dst = (z & 1) ? kd : qd;
  const int tid = threadIdx.x;
  const float* sp = src + ((size_t)b * D_ + h * DH_) * (size_t)SK_ + s0;
  const int sg = (tid & 15) * 4;
  int dloc = tid >> 4;
  for (int it = 0; it < 4; ++it, dloc += 16) {
    const float4 f = *reinterpret_cast<const float4*>(sp + (size_t)dloc * SK_ + sg);
    t[sg + 0][dloc] = f2bf(f.x);
    t[sg + 1][dloc] = f2bf(f.y);
    t[sg + 2][dloc] = f2bf(f.z);
    t[sg + 3][dloc] = f2bf(f.w);
  }
  __syncthreads();
  short* dp = dst + ((size_t)(b * H_ + h) * SQ_ + s0) * 64;
  for (int it = 0; it < 4; ++it) {
    const int c = tid + 256 * it;
    const int ss = c >> 4, pos = (c & 15) * 4;
    *reinterpret_cast<short4*>(dp + (size_t)ss * 64 + pos) =
        *reinterpret_cast<const short4*>(&t[ss][pos]);
  }
}

// Swapped-operand 32x32 flash attention, fixed-max softmax (P = exp2(s-24)).
// 4 waves, wave pid owns 32 q-rows; K/V tiles staged per-iter into LDS via
// global_load_lds (linear dest, source pre-swizzled c16^=row&7), double-buffered.
__global__ __launch_bounds__(256) void attn_kernel(
    short* __restrict__ xqT,            // [B][H][SQ][64] bf16: in qT, out x
    const short* __restrict__ kT,       // [B][H][SK][64] bf16
    const short* __restrict__ vb,       // [B][D][SK] bf16
    const float* __restrict__ gamma, const float* __restrict__ beta,
    const float* __restrict__ m_qk, const float* __restrict__ s_qk,
    const float2* __restrict__ msv, const float* __restrict__ kbias)
{
  __shared__ float bias_s[SK_];
  __shared__ short kbuf[2][4096];       // 64 rows x 64 shorts (128B/row), swizzled image
  __shared__ short vbuf[2][4096];

  // bijective XCD swizzle: the 4 q-tiles of one (b,h) land on one XCD
  const int bid = blockIdx.x;
  const int xcd = bid & 7, ixc = bid >> 3;
  const int grp = xcd * 32 + (ixc >> 2);   // (b,h) group 0..255
  const int qt  = ixc & 3;
  const int h = grp & 7, b = grp >> 3;

  const int tid = threadIdx.x, w = tid >> 6, l = tid & 63;
  const int l31 = l & 31, hi = l >> 5;
  const int swz = l31 & 7;

  const float gh = gamma[h], be = beta[h], mq = m_qk[h], sq = s_qk[h];
  const float a2 = gh / (sq * 8.0f) * LOG2E_;
  const float c2 = (be - mq * gh / sq) * LOG2E_ - FIXED_MAX_;

  const size_t bh = (size_t)(b * H_ + h);
  short* qbase = xqT + (bh * SQ_ + qt * 128 + w * 32) * 64;
  const short* kbase = kT + bh * SK_ * 64;
  const short* vbase = vb + ((size_t)b * D_ + h * DH_) * (size_t)SK_;

  // staging geometry: wave w stages chunks {2w, 2w+1} of K and V (1KB each)
  const int rsub = l >> 3;              // 0..7: row within chunk
  const int c16s = (l & 7) ^ rsub;      // swizzled 16B col in source

  auto stage = [&](int bufi, int it) {
    const int k0 = it * 64;
    for (int j = 0; j < 2; ++j) {
      const int ck = w * 2 + j;
      gload16(kbase + (size_t)(k0 + ck * 8 + rsub) * 64 + c16s * 8,
              &kbuf[bufi][ck * 512]);
      gload16(vbase + (size_t)(ck * 8 + rsub) * SK_ + k0 + c16s * 8,
              &vbuf[bufi][ck * 512]);
    }
  };

  stage(0, 0);

  if (tid < 128) {
    floatx4 t = reinterpret_cast<const floatx4*>(kbias + (size_t)b * SK_)[tid];
    t += c2;                             // fold affine offset + fixed max
    reinterpret_cast<floatx4*>(bias_s)[tid] = t;
  }

  // Q fragments (B-operand): lane holds q=l31, d = st*16 + hi*8 + 0..7
  short8 qf[4];
  for (int st = 0; st < 4; ++st)
    qf[st] = *reinterpret_cast<const short8*>(qbase + (size_t)l31 * 64 + st * 16 + hi * 8);

  floatx16 oacc[2];
  for (int i = 0; i < 16; ++i) { oacc[0][i] = 0.f; oacc[1][i] = 0.f; }
  float lpart = 0.f;

  __syncthreads();                       // drains prologue stage (vmcnt 0)

  int buf = 0;
  for (int it = 0; it < 8; ++it) {
    if (it < 7) stage(buf ^ 1, it + 1);  // issue next tile; latency hides under compute

    const int k0 = it * 64;
    const short* kl = kbuf[buf];
    const short* vl = vbuf[buf];

    // ---- S^T = K Q (fragments from swizzled LDS) ----
    floatx16 s0, s1;
    for (int i = 0; i < 16; ++i) { s0[i] = 0.f; s1[i] = 0.f; }
    __builtin_amdgcn_s_setprio(1);
    for (int st = 0; st < 4; ++st) {
      const short8 ka = *reinterpret_cast<const short8*>(
          &kl[(size_t)l31 * 64 + (((st << 1) | hi) ^ swz) * 8]);
      s0 = __builtin_amdgcn_mfma_f32_32x32x16_bf16(ka, qf[st], s0, 0, 0, 0);
    }
    for (int st = 0; st < 4; ++st) {
      const short8 kb = *reinterpret_cast<const short8*>(
          &kl[(size_t)(32 + l31) * 64 + (((st << 1) | hi) ^ swz) * 8]);
      s1 = __builtin_amdgcn_mfma_f32_32x32x16_bf16(kb, qf[st], s1, 0, 0, 0);
    }
    __builtin_amdgcn_s_setprio(0);

    // P = exp2(s*a2 + bias); reg r of sub -> k = sub*32 + 8*gg + 4*hi + r
    float p[32];
    for (int sub = 0; sub < 2; ++sub)
      for (int gg = 0; gg < 4; ++gg) {
        const floatx4 bv = *reinterpret_cast<const floatx4*>(
            &bias_s[k0 + sub * 32 + gg * 8 + hi * 4]);
        for (int r = 0; r < 4; ++r) {
          const float sc = sub ? s1[gg * 4 + r] : s0[gg * 4 + r];
          p[sub * 16 + gg * 4 + r] = exp2f(__builtin_fmaf(sc, a2, bv[r]));
        }
      }

    // partial row-sum (lane-local; cross-lane deferred to end)
    {
      float a16[16];
      for (int i = 0; i < 16; ++i) a16[i] = p[i] + p[i + 16];
      float a8[8];
      for (int i = 0; i < 8; ++i) a8[i] = a16[i] + a16[i + 8];
      lpart += ((a8[0] + a8[4]) + (a8[1] + a8[5])) + ((a8[2] + a8[6]) + (a8[3] + a8[7]));
    }

    // P -> bf16 words; word j holds (k=2j, k=2j+1) of this lane's k-set
    uint32_t Wd[16];
    for (int j = 0; j < 16; ++j) Wd[j] = cvt_pk_bf16(p[2 * j], p[2 * j + 1]);

    // PV: O^T[d][q] += V[d][k] * P[k][q]; cross-half P exchange via permlane32_swap
    __builtin_amdgcn_s_setprio(1);
    for (int kc = 0; kc < 4; ++kc) {
      const int base = (kc >> 1) * 8 + (kc & 1) * 4;
      uint32_t x0 = Wd[base + 0], x1 = Wd[base + 1];
      uint32_t y0 = Wd[base + 2], y1 = Wd[base + 3];
      plane32_swap(x0, y0);
      plane32_swap(x1, y1);
      union { uint32_t u[4]; short8 s; } pk;
      pk.u[0] = x0; pk.u[1] = x1; pk.u[2] = y0; pk.u[3] = y1;
      const short8 pb = pk.s;
      const short8 va0 = *reinterpret_cast<const short8*>(
          &vl[(size_t)l31 * 64 + (((kc << 1) | hi) ^ swz) * 8]);
      const short8 va1 = *reinterpret_cast<const short8*>(
          &vl[(size_t)(32 + l31) * 64 + (((kc << 1) | hi) ^ swz) * 8]);
      oacc[0] = __builtin_amdgcn_mfma_f32_32x32x16_bf16(va0, pb, oacc[0], 0, 0, 0);
      oacc[1] = __builtin_amdgcn_mfma_f32_32x32x16_bf16(va1, pb, oacc[1], 0, 0, 0);
    }
    __builtin_amdgcn_s_setprio(0);

    __syncthreads();                     // staged tile complete + buf consumers done
    buf ^= 1;
  }

  lpart += __shfl_xor(lpart, 32, 64);    // complete row sum

  // ---- epilogue: x = (q + O/l)*inv_s - m*inv_s, in place over qT ----
  const float invl = 1.0f / lpart;
  short* xr = qbase + (size_t)l31 * 64;
  const float2* msvh = msv + h * DH_;
  for (int dt = 0; dt < 2; ++dt)
    for (int gg = 0; gg < 4; ++gg) {
      const int d0 = dt * 32 + gg * 8 + hi * 4;
      const short4 q4 = *reinterpret_cast<const short4*>(xr + d0);
      const float2 c0 = msvh[d0 + 0], c1 = msvh[d0 + 1],
                   c2v = msvh[d0 + 2], c3 = msvh[d0 + 3];
      short4 xv;
      xv.x = f2bf((bf2f(q4.x) + oacc[dt][gg * 4 + 0] * invl) * c0.x - c0.y);
      xv.y = f2bf((bf2f(q4.y) + oacc[dt][gg * 4 + 1] * invl) * c1.x - c1.y);
      xv.z = f2bf((bf2f(q4.z) + oacc[dt][gg * 4 + 2] * invl) * c2v.x - c2v.y);
      xv.w = f2bf((bf2f(q4.w) + oacc[dt][gg * 4 + 3] * invl) * c3.x - c3.y);
      *reinterpret_cast<short4*>(xr + d0) = xv;
    }
}

// proj: out[b,o,q] = silu(bias[o] + sum_d W[o,d] x[b,q,d]); x layout [b][h][q][64].
__global__ __launch_bounds__(256) void proj_kernel(
    const short* __restrict__ Wb, const short* __restrict__ xT,
    const float* __restrict__ bias, float* __restrict__ out)
{
  __shared__ short xs[64 * 512];        // [row=q][c16, swizzled], 64 KB
  const int q0 = blockIdx.x * 64;
  const int o0 = blockIdx.y * 256;
  const int b  = blockIdx.z;
  const int tid = threadIdx.x, w = tid >> 6, l = tid & 63;
  const int l15 = l & 15, g = l >> 4;

  const short* xb = xT + (size_t)b * (H_ * SQ_ * 64);
  for (int hh = w * 2; hh < w * 2 + 2; ++hh) {
    const short* src = xb + ((size_t)hh * SQ_ + q0) * 64;
    for (int j = 0; j < 8; ++j) {
      const short8 val = *reinterpret_cast<const short8*>(src + j * 512 + l * 8);
      const int row = j * 8 + (l >> 3);
      const int c16 = (hh * 8 + (l & 7)) ^ (row & 7);
      *reinterpret_cast<short8*>(&xs[row * 512 + c16 * 8]) = val;
    }
  }
  __syncthreads();

  floatx4 acc[4][4];
  for (int ai = 0; ai < 4; ++ai)
    for (int bj = 0; bj < 4; ++bj)
      acc[ai][bj] = floatx4{0.f, 0.f, 0.f, 0.f};

  const short* wbase = Wb + (size_t)(o0 + w * 64 + l15) * D_;

  for (int step = 0; step < 16; ++step) {
    short8 af[4];
    for (int ai = 0; ai < 4; ++ai)
      af[ai] = *reinterpret_cast<const short8*>(
          wbase + (size_t)(ai * 16) * D_ + step * 32 + g * 8);
    short8 bf[4];
    for (int bj = 0; bj < 4; ++bj) {
      const int row = bj * 16 + l15;
      const int c16 = (step * 4 + g) ^ (row & 7);
      bf[bj] = *reinterpret_cast<const short8*>(&xs[row * 512 + c16 * 8]);
    }
    for (int ai = 0; ai < 4; ++ai)
      for (int bj = 0; bj < 4; ++bj)
        acc[ai][bj] = __builtin_amdgcn_mfma_f32_16x16x32_bf16(af[ai], bf[bj],
                                                              acc[ai][bj], 0, 0, 0);
  }

  for (int ai = 0; ai < 4; ++ai)
    for (int r = 0; r < 4; ++r) {
      const int o = o0 + w * 64 + ai * 16 + g * 4 + r;
      const float bo = bias[o];
      float* orow = out + ((size_t)b * D_ + o) * SQ_ + q0;
      for (int bj = 0; bj < 4; ++bj) {
        const float val = acc[ai][bj][r] + bo;
        orow[bj * 16 + l15] = val * (1.0f / (1.0f + __expf(-val)));
      }
    }
}

extern "C" void kernel_launch(void* const* d_in, const int* in_sizes, int n_in,
                              void* d_out, int out_size, void* d_ws, size_t ws_size,
                              hipStream_t stream) {
  const float*   q     = (const float*)d_in[0];
  const float*   k     = (const float*)d_in[1];
  const float*   v     = (const float*)d_in[2];
  const uint8_t* mask  = (const uint8_t*)d_in[3];
  const float*   gamma = (const float*)d_in[4];
  const float*   beta  = (const float*)d_in[5];
  const float*   m_qk  = (const float*)d_in[6];
  const float*   s_qk  = (const float*)d_in[7];
  const float*   m_v   = (const float*)d_in[8];
  const float*   s_v   = (const float*)d_in[9];
  const float*   W     = (const float*)d_in[10];
  const float*   bias  = (const float*)d_in[11];
  float* out = (float*)d_out;

  char* ws = (char*)d_ws;
  short*  Wb    = (short*)ws;                                   // 512 KB
  short*  xqT   = (short*)(ws + (1u << 19));                    // 16 MB
  short*  kTb   = (short*)(ws + (1u << 19) + (1u << 24));       // 16 MB
  short*  vbb   = (short*)(ws + (1u << 19) + 2u * (1u << 24));  // 16 MB
  float2* msv   = (float2*)(ws + (1u << 19) + 3u * (1u << 24)); // 4 KB
  int*    flag  = (int*)(ws + (1u << 19) + 3u * (1u << 24) + 4096);
  float*  kbias = (float*)(ws + (1u << 19) + 3u * (1u << 24) + 8192); // 64 KB

  detect_mask_kernel<<<1, 256, 0, stream>>>(mask, flag);
  bias_kernel<<<B_, 512, 0, stream>>>(mask, flag, kbias);
  msv_kernel<<<2, 256, 0, stream>>>(m_v, s_v, msv);
  convw_kernel<<<256, 256, 0, stream>>>(W, Wb);
  transpose2_kernel<<<dim3(8, 8, 64), 256, 0, stream>>>(q, k, xqT, kTb);
  convv_kernel<<<8192, 256, 0, stream>>>(v, vbb);
  attn_kernel<<<1024, 256, 0, stream>>>(xqT, kTb, vbb, gamma, beta,
                                        m_qk, s_qk, msv, kbias);
  proj_kernel<<<dim3(8, 2, 32), 256, 0, stream>>>(Wb, xqT, bias, out);
}

// Round 7
// 106.541 us; speedup vs baseline: 2.8531x; 1.1710x over previous
//
#include <hip/hip_runtime.h>
#include <hip/hip_bf16.h>
#include <cstdint>
#include <cstddef>

typedef __attribute__((ext_vector_type(8))) short short8;
typedef __attribute__((ext_vector_type(4))) float floatx4;
typedef __attribute__((ext_vector_type(16))) float floatx16;

#define B_ 32
#define H_ 8
#define D_ 512
#define DH_ 64
#define SQ_ 512
#define SK_ 512
#define NEG_INF_ -1000000000.0f
#define LOG2E_ 1.4426950408889634f
#define FIXED_MAX_ 24.0f

__device__ __forceinline__ short f2bf(float f) {
  union { float f; uint32_t u; } x; x.f = f;
  uint32_t r = x.u + 0x7FFFu + ((x.u >> 16) & 1u);
  return (short)(r >> 16);
}
__device__ __forceinline__ float bf2f(short s) {
  union { uint32_t u; float f; } x; x.u = ((uint32_t)(uint16_t)s) << 16;
  return x.f;
}
__device__ __forceinline__ uint32_t cvt_pk_bf16(float lo, float hi) {
  uint32_t r;
  asm("v_cvt_pk_bf16_f32 %0, %1, %2" : "=v"(r) : "v"(lo), "v"(hi));
  return r;
}
// Swap upper-half lanes of a with lower-half lanes of b (both modified).
__device__ __forceinline__ void plane32_swap(uint32_t& a, uint32_t& b) {
  asm("v_permlane32_swap_b32 %0, %1" : "+v"(a), "+v"(b));
}
// Async global->LDS, 16B per lane. LDS dest = uniform base + lane*16 (linear);
// global src is per-lane (swizzle goes on the source side — G21/m173).
__device__ __forceinline__ void gload16(const void* g, void* lds) {
  __builtin_amdgcn_global_load_lds(
      (const __attribute__((address_space(1))) void*)g,
      (__attribute__((address_space(3))) void*)lds, 16, 0, 0);
}

// Detect mask element layout: int32 (flag=0) vs byte/bool (flag=1).
__global__ void detect_mask_kernel(const uint8_t* __restrict__ m, int* __restrict__ flag) {
  __shared__ int found;
  if (threadIdx.x == 0) found = 0;
  __syncthreads();
  int any = 0;
  for (int i = threadIdx.x; i < B_ * SK_; i += 256) {
    if ((i & 3) != 0 && m[i] != 0) any = 1;
  }
  if (any) atomicOr(&found, 1);
  __syncthreads();
  if (threadIdx.x == 0) *flag = found;
}

// Fused small prep (512 thr): blocks 0-31 mask->bias row; 32: msv; 33-160: W->bf16.
__global__ __launch_bounds__(512) void prep_kernel(
    const uint8_t* __restrict__ mask8, const int* __restrict__ flag,
    float* __restrict__ kbias,
    const float* __restrict__ m_v, const float* __restrict__ s_v,
    float2* __restrict__ msv,
    const float* __restrict__ W, short* __restrict__ Wb) {
  const int blk = blockIdx.x, t = threadIdx.x;
  if (blk < 32) {
    int mv;
    if (*flag) mv = mask8[blk * SK_ + t];
    else       mv = reinterpret_cast<const int*>(mask8)[blk * SK_ + t];
    kbias[blk * SK_ + t] = mv ? NEG_INF_ * LOG2E_ : 0.0f;
  } else if (blk == 32) {
    const float inv = 1.0f / s_v[t];
    msv[t] = make_float2(inv, m_v[t] * inv);
  } else {
    const int i = (blk - 33) * 512 + t;
    const float4 f = reinterpret_cast<const float4*>(W)[i];
    short4 s;
    s.x = f2bf(f.x); s.y = f2bf(f.y); s.z = f2bf(f.z); s.w = f2bf(f.w);
    reinterpret_cast<short4*>(Wb)[i] = s;
  }
}

__global__ void convv_kernel(const float* __restrict__ v, short* __restrict__ vb) {
  const int i = blockIdx.x * 256 + threadIdx.x;
  const float4 f = reinterpret_cast<const float4*>(v)[i];
  short4 s;
  s.x = f2bf(f.x); s.y = f2bf(f.y); s.z = f2bf(f.z); s.w = f2bf(f.w);
  reinterpret_cast<short4*>(vb)[i] = s;
}

// k transpose: src f32 [B][D][S] -> dst bf16 [B][H][S][64]
__global__ __launch_bounds__(256) void transposek_kernel(const float* __restrict__ src,
                                                         short* __restrict__ dst) {
  __shared__ short t[64][68];
  const int s0 = blockIdx.x * 64, h = blockIdx.y, b = blockIdx.z;
  const int tid = threadIdx.x;
  const float* sp = src + ((size_t)b * D_ + h * DH_) * (size_t)SK_ + s0;
  const int sg = (tid & 15) * 4;
  int dloc = tid >> 4;
  for (int it = 0; it < 4; ++it, dloc += 16) {
    const float4 f = *reinterpret_cast<const float4*>(sp + (size_t)dloc * SK_ + sg);
    t[sg + 0][dloc] = f2bf(f.x);
    t[sg + 1][dloc] = f2bf(f.y);
    t[sg + 2][dloc] = f2bf(f.z);
    t[sg + 3][dloc] = f2bf(f.w);
  }
  __syncthreads();
  short* dp = dst + ((size_t)(b * H_ + h) * SQ_ + s0) * 64;
  for (int it = 0; it < 4; ++it) {
    const int c = tid + 256 * it;
    const int ss = c >> 4, pos = (c & 15) * 4;
    *reinterpret_cast<short4*>(dp + (size_t)ss * 64 + pos) =
        *reinterpret_cast<const short4*>(&t[ss][pos]);
  }
}

// Swapped-operand 32x32 flash attention, fixed-max softmax (P = exp2(s-24)).
// 4 waves, wave w owns 32 q-rows; Q fragments direct from f32 q (once);
// K/V staged per-iter into LDS via global_load_lds (source-swizzled), dbuf.
__global__ __launch_bounds__(256) void attn_kernel(
    const float* __restrict__ qf32,     // [B][D][SQ] f32
    short* __restrict__ xqT,            // out x: [B][H][SQ][64] bf16
    const short* __restrict__ kT,       // [B][H][SK][64] bf16
    const short* __restrict__ vb,       // [B][D][SK] bf16
    const float* __restrict__ gamma, const float* __restrict__ beta,
    const float* __restrict__ m_qk, const float* __restrict__ s_qk,
    const float2* __restrict__ msv, const float* __restrict__ kbias)
{
  __shared__ float bias_s[SK_];
  __shared__ short kbuf[2][4096];       // 64 rows x 64 shorts, swizzled image
  __shared__ short vbuf[2][4096];

  // bijective XCD swizzle: the 4 q-tiles of one (b,h) land on one XCD
  const int bid = blockIdx.x;
  const int xcd = bid & 7, ixc = bid >> 3;
  const int grp = xcd * 32 + (ixc >> 2);   // (b,h) group 0..255
  const int qt  = ixc & 3;
  const int h = grp & 7, b = grp >> 3;

  const int tid = threadIdx.x, w = tid >> 6, l = tid & 63;
  const int l31 = l & 31, hi = l >> 5;
  const int swz = l31 & 7;

  const float gh = gamma[h], be = beta[h], mq = m_qk[h], sq = s_qk[h];
  const float a2 = gh / (sq * 8.0f) * LOG2E_;
  const float c2 = (be - mq * gh / sq) * LOG2E_ - FIXED_MAX_;

  const size_t bh = (size_t)(b * H_ + h);
  const int qidx = qt * 128 + w * 32 + l31;
  const short* kbase = kT + bh * SK_ * 64;
  const short* vbase = vb + ((size_t)b * D_ + h * DH_) * (size_t)SK_;
  const float* qsrc = qf32 + ((size_t)b * D_ + h * DH_) * (size_t)SQ_ + qidx;

  // staging geometry: wave w stages chunks {2w, 2w+1} of K and V (1KB each)
  const int rsub = l >> 3;              // 0..7: row within chunk
  const int c16s = (l & 7) ^ rsub;      // swizzled 16B col in source

  auto stage = [&](int bufi, int it) {
    const int k0 = it * 64;
    for (int j = 0; j < 2; ++j) {
      const int ck = w * 2 + j;
      gload16(kbase + (size_t)(k0 + ck * 8 + rsub) * 64 + c16s * 8,
              &kbuf[bufi][ck * 512]);
      gload16(vbase + (size_t)(ck * 8 + rsub) * SK_ + k0 + c16s * 8,
              &vbuf[bufi][ck * 512]);
    }
  };

  stage(0, 0);

  if (tid < 128) {
    floatx4 t = reinterpret_cast<const floatx4*>(kbias + (size_t)b * SK_)[tid];
    t += c2;                             // fold affine offset + fixed max
    reinterpret_cast<floatx4*>(bias_s)[tid] = t;
  }

  // Q fragments (B-operand) direct from f32: lane q=qidx, d = st*16 + hi*8 + j
  short8 qf[4];
  for (int st = 0; st < 4; ++st) {
    float fv[8];
    for (int j = 0; j < 8; ++j)
      fv[j] = qsrc[(size_t)(st * 16 + hi * 8 + j) * SQ_];
    union { uint32_t u[4]; short8 s; } qk;
    for (int j2 = 0; j2 < 4; ++j2)
      qk.u[j2] = cvt_pk_bf16(fv[2 * j2], fv[2 * j2 + 1]);
    qf[st] = qk.s;
  }

  floatx16 oacc[2];
  for (int i = 0; i < 16; ++i) { oacc[0][i] = 0.f; oacc[1][i] = 0.f; }
  float lpart = 0.f;

  __syncthreads();                       // drains prologue stage

  int buf = 0;
  for (int it = 0; it < 8; ++it) {
    if (it < 7) stage(buf ^ 1, it + 1);  // issue next tile; hides under compute

    const int k0 = it * 64;
    const short* kl = kbuf[buf];
    const short* vl = vbuf[buf];

    // ---- S^T = K Q (fragments from swizzled LDS) ----
    floatx16 s0, s1;
    for (int i = 0; i < 16; ++i) { s0[i] = 0.f; s1[i] = 0.f; }
    __builtin_amdgcn_s_setprio(1);
    for (int st = 0; st < 4; ++st) {
      const short8 ka = *reinterpret_cast<const short8*>(
          &kl[(size_t)l31 * 64 + (((st << 1) | hi) ^ swz) * 8]);
      s0 = __builtin_amdgcn_mfma_f32_32x32x16_bf16(ka, qf[st], s0, 0, 0, 0);
    }
    for (int st = 0; st < 4; ++st) {
      const short8 kb = *reinterpret_cast<const short8*>(
          &kl[(size_t)(32 + l31) * 64 + (((st << 1) | hi) ^ swz) * 8]);
      s1 = __builtin_amdgcn_mfma_f32_32x32x16_bf16(kb, qf[st], s1, 0, 0, 0);
    }
    __builtin_amdgcn_s_setprio(0);

    // P = exp2(s*a2 + bias) — raw v_exp_f32; masked: exp2(-1.4e9) = 0 exactly
    float p[32];
    for (int sub = 0; sub < 2; ++sub)
      for (int gg = 0; gg < 4; ++gg) {
        const floatx4 bv = *reinterpret_cast<const floatx4*>(
            &bias_s[k0 + sub * 32 + gg * 8 + hi * 4]);
        for (int r = 0; r < 4; ++r) {
          const float sc = sub ? s1[gg * 4 + r] : s0[gg * 4 + r];
          p[sub * 16 + gg * 4 + r] =
              __builtin_amdgcn_exp2f(__builtin_fmaf(sc, a2, bv[r]));
        }
      }

    // partial row-sum (lane-local; cross-lane deferred to end)
    {
      float a16[16];
      for (int i = 0; i < 16; ++i) a16[i] = p[i] + p[i + 16];
      float a8[8];
      for (int i = 0; i < 8; ++i) a8[i] = a16[i] + a16[i + 8];
      lpart += ((a8[0] + a8[4]) + (a8[1] + a8[5])) + ((a8[2] + a8[6]) + (a8[3] + a8[7]));
    }

    // P -> bf16 words; word j holds (k=2j, k=2j+1) of this lane's k-set
    uint32_t Wd[16];
    for (int j = 0; j < 16; ++j) Wd[j] = cvt_pk_bf16(p[2 * j], p[2 * j + 1]);

    // PV: O^T[d][q] += V[d][k] * P[k][q]; cross-half exchange via permlane32_swap
    __builtin_amdgcn_s_setprio(1);
    for (int kc = 0; kc < 4; ++kc) {
      const int base = (kc >> 1) * 8 + (kc & 1) * 4;
      uint32_t x0 = Wd[base + 0], x1 = Wd[base + 1];
      uint32_t y0 = Wd[base + 2], y1 = Wd[base + 3];
      plane32_swap(x0, y0);
      plane32_swap(x1, y1);
      union { uint32_t u[4]; short8 s; } pk;
      pk.u[0] = x0; pk.u[1] = x1; pk.u[2] = y0; pk.u[3] = y1;
      const short8 pb = pk.s;
      const short8 va0 = *reinterpret_cast<const short8*>(
          &vl[(size_t)l31 * 64 + (((kc << 1) | hi) ^ swz) * 8]);
      const short8 va1 = *reinterpret_cast<const short8*>(
          &vl[(size_t)(32 + l31) * 64 + (((kc << 1) | hi) ^ swz) * 8]);
      oacc[0] = __builtin_amdgcn_mfma_f32_32x32x16_bf16(va0, pb, oacc[0], 0, 0, 0);
      oacc[1] = __builtin_amdgcn_mfma_f32_32x32x16_bf16(va1, pb, oacc[1], 0, 0, 0);
    }
    __builtin_amdgcn_s_setprio(0);

    __syncthreads();                     // staged tile complete + buf consumers done
    buf ^= 1;
  }

  lpart += __shfl_xor(lpart, 32, 64);    // complete row sum

  // ---- epilogue: x = (q + O/l)*inv_s - m*inv_s; residual q re-read f32 (L1-hot) ----
  const float invl = __builtin_amdgcn_rcpf(lpart);
  short* xr = xqT + (bh * SQ_ + qidx) * 64;
  const float2* msvh = msv + h * DH_;
  for (int dt = 0; dt < 2; ++dt)
    for (int gg = 0; gg < 4; ++gg) {
      const int d0 = dt * 32 + gg * 8 + hi * 4;
      float qv[4];
      for (int r = 0; r < 4; ++r) qv[r] = qsrc[(size_t)(d0 + r) * SQ_];
      const float2 c0 = msvh[d0 + 0], c1 = msvh[d0 + 1],
                   c2v = msvh[d0 + 2], c3 = msvh[d0 + 3];
      short4 xv;
      xv.x = f2bf((qv[0] + oacc[dt][gg * 4 + 0] * invl) * c0.x - c0.y);
      xv.y = f2bf((qv[1] + oacc[dt][gg * 4 + 1] * invl) * c1.x - c1.y);
      xv.z = f2bf((qv[2] + oacc[dt][gg * 4 + 2] * invl) * c2v.x - c2v.y);
      xv.w = f2bf((qv[3] + oacc[dt][gg * 4 + 3] * invl) * c3.x - c3.y);
      *reinterpret_cast<short4*>(xr + d0) = xv;
    }
}

// proj: out[b,o,q] = silu(bias[o] + sum_d W[o,d] x[b,q,d]); x layout [b][h][q][64].
__global__ __launch_bounds__(256) void proj_kernel(
    const short* __restrict__ Wb, const short* __restrict__ xT,
    const float* __restrict__ bias, float* __restrict__ out)
{
  __shared__ short xs[64 * 512];        // [row=q][c16, swizzled], 64 KB
  const int q0 = blockIdx.x * 64;
  const int o0 = blockIdx.y * 256;
  const int b  = blockIdx.z;
  const int tid = threadIdx.x, w = tid >> 6, l = tid & 63;
  const int l15 = l & 15, g = l >> 4;

  const short* xb = xT + (size_t)b * (H_ * SQ_ * 64);
  for (int hh = w * 2; hh < w * 2 + 2; ++hh) {
    const short* src = xb + ((size_t)hh * SQ_ + q0) * 64;
    for (int j = 0; j < 8; ++j) {
      const short8 val = *reinterpret_cast<const short8*>(src + j * 512 + l * 8);
      const int row = j * 8 + (l >> 3);
      const int c16 = (hh * 8 + (l & 7)) ^ (row & 7);
      *reinterpret_cast<short8*>(&xs[row * 512 + c16 * 8]) = val;
    }
  }
  __syncthreads();

  floatx4 acc[4][4];
  for (int ai = 0; ai < 4; ++ai)
    for (int bj = 0; bj < 4; ++bj)
      acc[ai][bj] = floatx4{0.f, 0.f, 0.f, 0.f};

  const short* wbase = Wb + (size_t)(o0 + w * 64 + l15) * D_;

  for (int step = 0; step < 16; ++step) {
    short8 af[4];
    for (int ai = 0; ai < 4; ++ai)
      af[ai] = *reinterpret_cast<const short8*>(
          wbase + (size_t)(ai * 16) * D_ + step * 32 + g * 8);
    short8 bf[4];
    for (int bj = 0; bj < 4; ++bj) {
      const int row = bj * 16 + l15;
      const int c16 = (step * 4 + g) ^ (row & 7);
      bf[bj] = *reinterpret_cast<const short8*>(&xs[row * 512 + c16 * 8]);
    }
    for (int ai = 0; ai < 4; ++ai)
      for (int bj = 0; bj < 4; ++bj)
        acc[ai][bj] = __builtin_amdgcn_mfma_f32_16x16x32_bf16(af[ai], bf[bj],
                                                              acc[ai][bj], 0, 0, 0);
  }

  for (int ai = 0; ai < 4; ++ai)
    for (int r = 0; r < 4; ++r) {
      const int o = o0 + w * 64 + ai * 16 + g * 4 + r;
      const float bo = bias[o];
      float* orow = out + ((size_t)b * D_ + o) * SQ_ + q0;
      for (int bj = 0; bj < 4; ++bj) {
        const float val = acc[ai][bj][r] + bo;
        orow[bj * 16 + l15] =
            val * __builtin_amdgcn_rcpf(1.0f + __expf(-val));
      }
    }
}

extern "C" void kernel_launch(void* const* d_in, const int* in_sizes, int n_in,
                              void* d_out, int out_size, void* d_ws, size_t ws_size,
                              hipStream_t stream) {
  const float*   q     = (const float*)d_in[0];
  const float*   k     = (const float*)d_in[1];
  const float*   v     = (const float*)d_in[2];
  const uint8_t* mask  = (const uint8_t*)d_in[3];
  const float*   gamma = (const float*)d_in[4];
  const float*   beta  = (const float*)d_in[5];
  const float*   m_qk  = (const float*)d_in[6];
  const float*   s_qk  = (const float*)d_in[7];
  const float*   m_v   = (const float*)d_in[8];
  const float*   s_v   = (const float*)d_in[9];
  const float*   W     = (const float*)d_in[10];
  const float*   bias  = (const float*)d_in[11];
  float* out = (float*)d_out;

  char* ws = (char*)d_ws;
  short*  Wb    = (short*)ws;                                   // 512 KB
  short*  xqT   = (short*)(ws + (1u << 19));                    // 16 MB (x output)
  short*  kTb   = (short*)(ws + (1u << 19) + (1u << 24));       // 16 MB
  short*  vbb   = (short*)(ws + (1u << 19) + 2u * (1u << 24));  // 16 MB
  float2* msv   = (float2*)(ws + (1u << 19) + 3u * (1u << 24)); // 4 KB
  int*    flag  = (int*)(ws + (1u << 19) + 3u * (1u << 24) + 4096);
  float*  kbias = (float*)(ws + (1u << 19) + 3u * (1u << 24) + 8192); // 64 KB

  detect_mask_kernel<<<1, 256, 0, stream>>>(mask, flag);
  prep_kernel<<<161, 512, 0, stream>>>(mask, flag, kbias, m_v, s_v, msv, W, Wb);
  transposek_kernel<<<dim3(8, 8, 32), 256, 0, stream>>>(k, kTb);
  convv_kernel<<<8192, 256, 0, stream>>>(v, vbb);
  attn_kernel<<<1024, 256, 0, stream>>>(q, xqT, kTb, vbb, gamma, beta,
                                        m_qk, s_qk, msv, kbias);
  proj_kernel<<<dim3(8, 2, 32), 256, 0, stream>>>(Wb, xqT, bias, out);
}

// Round 8
// 105.774 us; speedup vs baseline: 2.8738x; 1.0073x over previous
//
#include <hip/hip_runtime.h>
#include <hip/hip_bf16.h>
#include <cstdint>
#include <cstddef>

typedef __attribute__((ext_vector_type(8))) short short8;
typedef __attribute__((ext_vector_type(4))) float floatx4;
typedef __attribute__((ext_vector_type(16))) float floatx16;

#define B_ 32
#define H_ 8
#define D_ 512
#define DH_ 64
#define SQ_ 512
#define SK_ 512
#define NEG_INF_ -1000000000.0f
#define LOG2E_ 1.4426950408889634f
#define FIXED_MAX_ 24.0f

__device__ __forceinline__ short f2bf(float f) {
  union { float f; uint32_t u; } x; x.f = f;
  uint32_t r = x.u + 0x7FFFu + ((x.u >> 16) & 1u);
  return (short)(r >> 16);
}
__device__ __forceinline__ float bf2f(short s) {
  union { uint32_t u; float f; } x; x.u = ((uint32_t)(uint16_t)s) << 16;
  return x.f;
}
__device__ __forceinline__ uint32_t cvt_pk_bf16(float lo, float hi) {
  uint32_t r;
  asm("v_cvt_pk_bf16_f32 %0, %1, %2" : "=v"(r) : "v"(lo), "v"(hi));
  return r;
}
// Swap upper-half lanes of a with lower-half lanes of b (both modified).
__device__ __forceinline__ void plane32_swap(uint32_t& a, uint32_t& b) {
  asm("v_permlane32_swap_b32 %0, %1" : "+v"(a), "+v"(b));
}
// Async global->LDS, 16B per lane. LDS dest = uniform base + lane*16 (linear);
// global src is per-lane (swizzle goes on the source side — G21/m173).
__device__ __forceinline__ void gload16(const void* g, void* lds) {
  __builtin_amdgcn_global_load_lds(
      (const __attribute__((address_space(1))) void*)g,
      (__attribute__((address_space(3))) void*)lds, 16, 0, 0);
}

// Detect mask element layout: int32 (flag=0) vs byte/bool (flag=1).
__global__ void detect_mask_kernel(const uint8_t* __restrict__ m, int* __restrict__ flag) {
  __shared__ int found;
  if (threadIdx.x == 0) found = 0;
  __syncthreads();
  int any = 0;
  for (int i = threadIdx.x; i < B_ * SK_; i += 256) {
    if ((i & 3) != 0 && m[i] != 0) any = 1;
  }
  if (any) atomicOr(&found, 1);
  __syncthreads();
  if (threadIdx.x == 0) *flag = found;
}

// Fused small prep (512 thr): blocks 0-31 mask->bias row; 32: msv; 33-160: W->bf16.
__global__ __launch_bounds__(512) void prep_kernel(
    const uint8_t* __restrict__ mask8, const int* __restrict__ flag,
    float* __restrict__ kbias,
    const float* __restrict__ m_v, const float* __restrict__ s_v,
    float2* __restrict__ msv,
    const float* __restrict__ W, short* __restrict__ Wb) {
  const int blk = blockIdx.x, t = threadIdx.x;
  if (blk < 32) {
    int mv;
    if (*flag) mv = mask8[blk * SK_ + t];
    else       mv = reinterpret_cast<const int*>(mask8)[blk * SK_ + t];
    kbias[blk * SK_ + t] = mv ? NEG_INF_ * LOG2E_ : 0.0f;
  } else if (blk == 32) {
    const float inv = 1.0f / s_v[t];
    msv[t] = make_float2(inv, m_v[t] * inv);
  } else {
    const int i = (blk - 33) * 512 + t;
    const float4 f = reinterpret_cast<const float4*>(W)[i];
    short4 s;
    s.x = f2bf(f.x); s.y = f2bf(f.y); s.z = f2bf(f.z); s.w = f2bf(f.w);
    reinterpret_cast<short4*>(Wb)[i] = s;
  }
}

__global__ void convv_kernel(const float* __restrict__ v, short* __restrict__ vb) {
  const int i = blockIdx.x * 256 + threadIdx.x;
  const float4 f = reinterpret_cast<const float4*>(v)[i];
  short4 s;
  s.x = f2bf(f.x); s.y = f2bf(f.y); s.z = f2bf(f.z); s.w = f2bf(f.w);
  reinterpret_cast<short4*>(vb)[i] = s;
}

// k transpose: src f32 [B][D][S] -> dst bf16 [B][H][S][64]
__global__ __launch_bounds__(256) void transposek_kernel(const float* __restrict__ src,
                                                         short* __restrict__ dst) {
  __shared__ short t[64][68];
  const int s0 = blockIdx.x * 64, h = blockIdx.y, b = blockIdx.z;
  const int tid = threadIdx.x;
  const float* sp = src + ((size_t)b * D_ + h * DH_) * (size_t)SK_ + s0;
  const int sg = (tid & 15) * 4;
  int dloc = tid >> 4;
  for (int it = 0; it < 4; ++it, dloc += 16) {
    const float4 f = *reinterpret_cast<const float4*>(sp + (size_t)dloc * SK_ + sg);
    t[sg + 0][dloc] = f2bf(f.x);
    t[sg + 1][dloc] = f2bf(f.y);
    t[sg + 2][dloc] = f2bf(f.z);
    t[sg + 3][dloc] = f2bf(f.w);
  }
  __syncthreads();
  short* dp = dst + ((size_t)(b * H_ + h) * SQ_ + s0) * 64;
  for (int it = 0; it < 4; ++it) {
    const int c = tid + 256 * it;
    const int ss = c >> 4, pos = (c & 15) * 4;
    *reinterpret_cast<short4*>(dp + (size_t)ss * 64 + pos) =
        *reinterpret_cast<const short4*>(&t[ss][pos]);
  }
}

// Swapped-operand 32x32 flash attention, fixed-max softmax (P = exp2(s-24)).
// 4 waves, wave w owns 32 q-rows. K/V staged via global_load_lds into a 3-buffer
// ring, 2 tiles in flight, counted s_waitcnt vmcnt(4) + raw s_barrier (T4):
// loads span barriers, never drained to 0 in the main loop.
__global__ __launch_bounds__(256) void attn_kernel(
    const float* __restrict__ qf32,     // [B][D][SQ] f32
    short* __restrict__ xqT,            // out x: [B][H][SQ][64] bf16
    const short* __restrict__ kT,       // [B][H][SK][64] bf16
    const short* __restrict__ vb,       // [B][D][SK] bf16
    const float* __restrict__ gamma, const float* __restrict__ beta,
    const float* __restrict__ m_qk, const float* __restrict__ s_qk,
    const float2* __restrict__ msv, const float* __restrict__ kbias)
{
  __shared__ float bias_s[SK_];
  __shared__ short kbuf[3][4096];       // 64 rows x 64 shorts, swizzled image
  __shared__ short vbuf[3][4096];

  // bijective XCD swizzle: the 4 q-tiles of one (b,h) land on one XCD
  const int bid = blockIdx.x;
  const int xcd = bid & 7, ixc = bid >> 3;
  const int grp = xcd * 32 + (ixc >> 2);   // (b,h) group 0..255
  const int qt  = ixc & 3;
  const int h = grp & 7, b = grp >> 3;

  const int tid = threadIdx.x, w = tid >> 6, l = tid & 63;
  const int l31 = l & 31, hi = l >> 5;
  const int swz = l31 & 7;

  const float gh = gamma[h], be = beta[h], mq = m_qk[h], sq = s_qk[h];
  const float a2 = gh / (sq * 8.0f) * LOG2E_;
  const float c2 = (be - mq * gh / sq) * LOG2E_ - FIXED_MAX_;

  const size_t bh = (size_t)(b * H_ + h);
  const int qidx = qt * 128 + w * 32 + l31;
  const short* kbase = kT + bh * SK_ * 64;
  const short* vbase = vb + ((size_t)b * D_ + h * DH_) * (size_t)SK_;
  const float* qsrc = qf32 + ((size_t)b * D_ + h * DH_) * (size_t)SQ_ + qidx;

  // Q fragments (B-operand) direct from f32 FIRST (so prologue vmcnt(4) is exact)
  short8 qf[4];
  for (int st = 0; st < 4; ++st) {
    float fv[8];
    for (int j = 0; j < 8; ++j)
      fv[j] = qsrc[(size_t)(st * 16 + hi * 8 + j) * SQ_];
    union { uint32_t u[4]; short8 s; } qk;
    for (int j2 = 0; j2 < 4; ++j2)
      qk.u[j2] = cvt_pk_bf16(fv[2 * j2], fv[2 * j2 + 1]);
    qf[st] = qk.s;
  }

  // staging geometry: wave w stages chunks {2w, 2w+1} of K and V (1KB each)
  const int rsub = l >> 3;              // 0..7: row within chunk
  const int c16s = (l & 7) ^ rsub;      // swizzled 16B col in source

  auto stage = [&](int bufi, int it) {
    const int k0 = it * 64;
    for (int j = 0; j < 2; ++j) {
      const int ck = w * 2 + j;
      gload16(kbase + (size_t)(k0 + ck * 8 + rsub) * 64 + c16s * 8,
              &kbuf[bufi][ck * 512]);
      gload16(vbase + (size_t)(ck * 8 + rsub) * SK_ + k0 + c16s * 8,
              &vbuf[bufi][ck * 512]);
    }
  };

  stage(0, 0);
  stage(1, 1);

  if (tid < 128) {
    floatx4 t = reinterpret_cast<const floatx4*>(kbias + (size_t)b * SK_)[tid];
    t += c2;                             // fold affine offset + fixed max
    reinterpret_cast<floatx4*>(bias_s)[tid] = t;
  }

  floatx16 oacc[2];
  for (int i = 0; i < 16; ++i) { oacc[0][i] = 0.f; oacc[1][i] = 0.f; }
  float lpart = 0.f;

  // prologue barrier: tile0 landed (vmcnt<=4 keeps tile1 in flight), bias visible
  asm volatile("s_waitcnt vmcnt(4) lgkmcnt(0)" ::: "memory");
  __builtin_amdgcn_s_barrier();
  __builtin_amdgcn_sched_barrier(0);

  int bc = 0;                            // buffer holding tile `it`
  for (int it = 0; it < 8; ++it) {
    if (it < 6) {
      const int bs = bc >= 1 ? bc - 1 : bc + 2;   // (bc+2)%3: consumed 2 iters ago
      stage(bs, it + 2);
    }

    const int k0 = it * 64;
    const short* kl = kbuf[bc];
    const short* vl = vbuf[bc];

    // ---- S^T = K Q (fragments from swizzled LDS) ----
    floatx16 s0, s1;
    for (int i = 0; i < 16; ++i) { s0[i] = 0.f; s1[i] = 0.f; }
    __builtin_amdgcn_s_setprio(1);
    for (int st = 0; st < 4; ++st) {
      const short8 ka = *reinterpret_cast<const short8*>(
          &kl[(size_t)l31 * 64 + (((st << 1) | hi) ^ swz) * 8]);
      s0 = __builtin_amdgcn_mfma_f32_32x32x16_bf16(ka, qf[st], s0, 0, 0, 0);
    }
    for (int st = 0; st < 4; ++st) {
      const short8 kb = *reinterpret_cast<const short8*>(
          &kl[(size_t)(32 + l31) * 64 + (((st << 1) | hi) ^ swz) * 8]);
      s1 = __builtin_amdgcn_mfma_f32_32x32x16_bf16(kb, qf[st], s1, 0, 0, 0);
    }
    __builtin_amdgcn_s_setprio(0);

    // P = exp2(s*a2 + bias) — raw v_exp_f32; masked: exp2(-1.4e9) = 0 exactly
    float p[32];
    for (int sub = 0; sub < 2; ++sub)
      for (int gg = 0; gg < 4; ++gg) {
        const floatx4 bv = *reinterpret_cast<const floatx4*>(
            &bias_s[k0 + sub * 32 + gg * 8 + hi * 4]);
        for (int r = 0; r < 4; ++r) {
          const float sc = sub ? s1[gg * 4 + r] : s0[gg * 4 + r];
          p[sub * 16 + gg * 4 + r] =
              __builtin_amdgcn_exp2f(__builtin_fmaf(sc, a2, bv[r]));
        }
      }

    // partial row-sum (lane-local; cross-lane deferred to end)
    {
      float a16[16];
      for (int i = 0; i < 16; ++i) a16[i] = p[i] + p[i + 16];
      float a8[8];
      for (int i = 0; i < 8; ++i) a8[i] = a16[i] + a16[i + 8];
      lpart += ((a8[0] + a8[4]) + (a8[1] + a8[5])) + ((a8[2] + a8[6]) + (a8[3] + a8[7]));
    }

    // P -> bf16 words; word j holds (k=2j, k=2j+1) of this lane's k-set
    uint32_t Wd[16];
    for (int j = 0; j < 16; ++j) Wd[j] = cvt_pk_bf16(p[2 * j], p[2 * j + 1]);

    // PV: O^T[d][q] += V[d][k] * P[k][q]; cross-half exchange via permlane32_swap
    __builtin_amdgcn_s_setprio(1);
    for (int kc = 0; kc < 4; ++kc) {
      const int base = (kc >> 1) * 8 + (kc & 1) * 4;
      uint32_t x0 = Wd[base + 0], x1 = Wd[base + 1];
      uint32_t y0 = Wd[base + 2], y1 = Wd[base + 3];
      plane32_swap(x0, y0);
      plane32_swap(x1, y1);
      union { uint32_t u[4]; short8 s; } pk;
      pk.u[0] = x0; pk.u[1] = x1; pk.u[2] = y0; pk.u[3] = y1;
      const short8 pb = pk.s;
      const short8 va0 = *reinterpret_cast<const short8*>(
          &vl[(size_t)l31 * 64 + (((kc << 1) | hi) ^ swz) * 8]);
      const short8 va1 = *reinterpret_cast<const short8*>(
          &vl[(size_t)(32 + l31) * 64 + (((kc << 1) | hi) ^ swz) * 8]);
      oacc[0] = __builtin_amdgcn_mfma_f32_32x32x16_bf16(va0, pb, oacc[0], 0, 0, 0);
      oacc[1] = __builtin_amdgcn_mfma_f32_32x32x16_bf16(va1, pb, oacc[1], 0, 0, 0);
    }
    __builtin_amdgcn_s_setprio(0);

    // counted-vmcnt barrier: tile it+1 landed; tile it+2 stays in flight
    if (it < 7) {
      if (it < 6) asm volatile("s_waitcnt vmcnt(4)" ::: "memory");
      else        asm volatile("s_waitcnt vmcnt(0)" ::: "memory");
      __builtin_amdgcn_s_barrier();
      __builtin_amdgcn_sched_barrier(0);
    }
    bc = bc == 2 ? 0 : bc + 1;
  }

  lpart += __shfl_xor(lpart, 32, 64);    // complete row sum

  // ---- epilogue: x = (q + O/l)*inv_s - m*inv_s; residual q re-read f32 (L2-hot) ----
  const float invl = __builtin_amdgcn_rcpf(lpart);
  short* xr = xqT + (bh * SQ_ + qidx) * 64;
  const float2* msvh = msv + h * DH_;
  for (int dt = 0; dt < 2; ++dt)
    for (int gg = 0; gg < 4; ++gg) {
      const int d0 = dt * 32 + gg * 8 + hi * 4;
      float qv[4];
      for (int r = 0; r < 4; ++r) qv[r] = qsrc[(size_t)(d0 + r) * SQ_];
      const float2 c0 = msvh[d0 + 0], c1 = msvh[d0 + 1],
                   c2v = msvh[d0 + 2], c3 = msvh[d0 + 3];
      short4 xv;
      xv.x = f2bf((qv[0] + oacc[dt][gg * 4 + 0] * invl) * c0.x - c0.y);
      xv.y = f2bf((qv[1] + oacc[dt][gg * 4 + 1] * invl) * c1.x - c1.y);
      xv.z = f2bf((qv[2] + oacc[dt][gg * 4 + 2] * invl) * c2v.x - c2v.y);
      xv.w = f2bf((qv[3] + oacc[dt][gg * 4 + 3] * invl) * c3.x - c3.y);
      *reinterpret_cast<short4*>(xr + d0) = xv;
    }
}

// proj: out[b,o,q] = silu(bias[o] + sum_d W[o,d] x[b,q,d]); x layout [b][h][q][64].
__global__ __launch_bounds__(256) void proj_kernel(
    const short* __restrict__ Wb, const short* __restrict__ xT,
    const float* __restrict__ bias, float* __restrict__ out)
{
  __shared__ short xs[64 * 512];        // [row=q][c16, swizzled], 64 KB
  const int q0 = blockIdx.x * 64;
  const int o0 = blockIdx.y * 256;
  const int b  = blockIdx.z;
  const int tid = threadIdx.x, w = tid >> 6, l = tid & 63;
  const int l15 = l & 15, g = l >> 4;

  const short* xb = xT + (size_t)b * (H_ * SQ_ * 64);
  for (int hh = w * 2; hh < w * 2 + 2; ++hh) {
    const short* src = xb + ((size_t)hh * SQ_ + q0) * 64;
    for (int j = 0; j < 8; ++j) {
      const short8 val = *reinterpret_cast<const short8*>(src + j * 512 + l * 8);
      const int row = j * 8 + (l >> 3);
      const int c16 = (hh * 8 + (l & 7)) ^ (row & 7);
      *reinterpret_cast<short8*>(&xs[row * 512 + c16 * 8]) = val;
    }
  }
  __syncthreads();

  floatx4 acc[4][4];
  for (int ai = 0; ai < 4; ++ai)
    for (int bj = 0; bj < 4; ++bj)
      acc[ai][bj] = floatx4{0.f, 0.f, 0.f, 0.f};

  const short* wbase = Wb + (size_t)(o0 + w * 64 + l15) * D_;

  for (int step = 0; step < 16; ++step) {
    short8 af[4];
    for (int ai = 0; ai < 4; ++ai)
      af[ai] = *reinterpret_cast<const short8*>(
          wbase + (size_t)(ai * 16) * D_ + step * 32 + g * 8);
    short8 bf[4];
    for (int bj = 0; bj < 4; ++bj) {
      const int row = bj * 16 + l15;
      const int c16 = (step * 4 + g) ^ (row & 7);
      bf[bj] = *reinterpret_cast<const short8*>(&xs[row * 512 + c16 * 8]);
    }
    for (int ai = 0; ai < 4; ++ai)
      for (int bj = 0; bj < 4; ++bj)
        acc[ai][bj] = __builtin_amdgcn_mfma_f32_16x16x32_bf16(af[ai], bf[bj],
                                                              acc[ai][bj], 0, 0, 0);
  }

  for (int ai = 0; ai < 4; ++ai)
    for (int r = 0; r < 4; ++r) {
      const int o = o0 + w * 64 + ai * 16 + g * 4 + r;
      const float bo = bias[o];
      float* orow = out + ((size_t)b * D_ + o) * SQ_ + q0;
      for (int bj = 0; bj < 4; ++bj) {
        const float val = acc[ai][bj][r] + bo;
        orow[bj * 16 + l15] =
            val * __builtin_amdgcn_rcpf(1.0f + __expf(-val));
      }
    }
}

extern "C" void kernel_launch(void* const* d_in, const int* in_sizes, int n_in,
                              void* d_out, int out_size, void* d_ws, size_t ws_size,
                              hipStream_t stream) {
  const float*   q     = (const float*)d_in[0];
  const float*   k     = (const float*)d_in[1];
  const float*   v     = (const float*)d_in[2];
  const uint8_t* mask  = (const uint8_t*)d_in[3];
  const float*   gamma = (const float*)d_in[4];
  const float*   beta  = (const float*)d_in[5];
  const float*   m_qk  = (const float*)d_in[6];
  const float*   s_qk  = (const float*)d_in[7];
  const float*   m_v   = (const float*)d_in[8];
  const float*   s_v   = (const float*)d_in[9];
  const float*   W     = (const float*)d_in[10];
  const float*   bias  = (const float*)d_in[11];
  float* out = (float*)d_out;

  char* ws = (char*)d_ws;
  short*  Wb    = (short*)ws;                                   // 512 KB
  short*  xqT   = (short*)(ws + (1u << 19));                    // 16 MB (x output)
  short*  kTb   = (short*)(ws + (1u << 19) + (1u << 24));       // 16 MB
  short*  vbb   = (short*)(ws + (1u << 19) + 2u * (1u << 24));  // 16 MB
  float2* msv   = (float2*)(ws + (1u << 19) + 3u * (1u << 24)); // 4 KB
  int*    flag  = (int*)(ws + (1u << 19) + 3u * (1u << 24) + 4096);
  float*  kbias = (float*)(ws + (1u << 19) + 3u * (1u << 24) + 8192); // 64 KB

  detect_mask_kernel<<<1, 256, 0, stream>>>(mask, flag);
  prep_kernel<<<161, 512, 0, stream>>>(mask, flag, kbias, m_v, s_v, msv, W, Wb);
  transposek_kernel<<<dim3(8, 8, 32), 256, 0, stream>>>(k, kTb);
  convv_kernel<<<8192, 256, 0, stream>>>(v, vbb);
  attn_kernel<<<1024, 256, 0, stream>>>(q, xqT, kTb, vbb, gamma, beta,
                                        m_qk, s_qk, msv, kbias);
  proj_kernel<<<dim3(8, 2, 32), 256, 0, stream>>>(Wb, xqT, bias, out);
}

// Round 9
// 100.895 us; speedup vs baseline: 3.0128x; 1.0484x over previous
//
#include <hip/hip_runtime.h>
#include <hip/hip_bf16.h>
#include <cstdint>
#include <cstddef>

typedef __attribute__((ext_vector_type(8))) short short8;
typedef __attribute__((ext_vector_type(4))) float floatx4;
typedef __attribute__((ext_vector_type(16))) float floatx16;

#define B_ 32
#define H_ 8
#define D_ 512
#define DH_ 64
#define SQ_ 512
#define SK_ 512
#define NEG_INF_ -1000000000.0f
#define LOG2E_ 1.4426950408889634f
#define FIXED_MAX_ 24.0f

__device__ __forceinline__ short f2bf(float f) {
  union { float f; uint32_t u; } x; x.f = f;
  uint32_t r = x.u + 0x7FFFu + ((x.u >> 16) & 1u);
  return (short)(r >> 16);
}
__device__ __forceinline__ float bf2f(short s) {
  union { uint32_t u; float f; } x; x.u = ((uint32_t)(uint16_t)s) << 16;
  return x.f;
}
__device__ __forceinline__ uint32_t cvt_pk_bf16(float lo, float hi) {
  uint32_t r;
  asm("v_cvt_pk_bf16_f32 %0, %1, %2" : "=v"(r) : "v"(lo), "v"(hi));
  return r;
}
// Swap upper-half lanes of a with lower-half lanes of b (both modified).
__device__ __forceinline__ void plane32_swap(uint32_t& a, uint32_t& b) {
  asm("v_permlane32_swap_b32 %0, %1" : "+v"(a), "+v"(b));
}
// Async global->LDS, 16B per lane. LDS dest = uniform base + lane*16 (linear);
// global src is per-lane (swizzle goes on the source side — G21/m173).
__device__ __forceinline__ void gload16(const void* g, void* lds) {
  __builtin_amdgcn_global_load_lds(
      (const __attribute__((address_space(1))) void*)g,
      (__attribute__((address_space(3))) void*)lds, 16, 0, 0);
}

// Detect mask element layout: int32 (flag=0) vs byte/bool (flag=1).
__global__ void detect_mask_kernel(const uint8_t* __restrict__ m, int* __restrict__ flag) {
  __shared__ int found;
  if (threadIdx.x == 0) found = 0;
  __syncthreads();
  int any = 0;
  for (int i = threadIdx.x; i < B_ * SK_; i += 256) {
    if ((i & 3) != 0 && m[i] != 0) any = 1;
  }
  if (any) atomicOr(&found, 1);
  __syncthreads();
  if (threadIdx.x == 0) *flag = found;
}

// Fused small prep (512 thr): blocks 0-31 mask->bias row; 32: msv; 33-160: W->bf16.
__global__ __launch_bounds__(512) void prep_kernel(
    const uint8_t* __restrict__ mask8, const int* __restrict__ flag,
    float* __restrict__ kbias,
    const float* __restrict__ m_v, const float* __restrict__ s_v,
    float2* __restrict__ msv,
    const float* __restrict__ W, short* __restrict__ Wb) {
  const int blk = blockIdx.x, t = threadIdx.x;
  if (blk < 32) {
    int mv;
    if (*flag) mv = mask8[blk * SK_ + t];
    else       mv = reinterpret_cast<const int*>(mask8)[blk * SK_ + t];
    kbias[blk * SK_ + t] = mv ? NEG_INF_ * LOG2E_ : 0.0f;
  } else if (blk == 32) {
    const float inv = 1.0f / s_v[t];
    msv[t] = make_float2(inv, m_v[t] * inv);
  } else {
    const int i = (blk - 33) * 512 + t;
    const float4 f = reinterpret_cast<const float4*>(W)[i];
    short4 s;
    s.x = f2bf(f.x); s.y = f2bf(f.y); s.z = f2bf(f.z); s.w = f2bf(f.w);
    reinterpret_cast<short4*>(Wb)[i] = s;
  }
}

// v [B][D][S] f32 -> bf16, grid-stride: 2048 blocks x 256 thr x 4 float4.
__global__ __launch_bounds__(256) void convv_kernel(const float* __restrict__ v,
                                                    short* __restrict__ vb) {
  const int base = blockIdx.x * 1024 + threadIdx.x;
  for (int j = 0; j < 4; ++j) {
    const int i = base + j * 256;
    const float4 f = reinterpret_cast<const float4*>(v)[i];
    short4 s;
    s.x = f2bf(f.x); s.y = f2bf(f.y); s.z = f2bf(f.z); s.w = f2bf(f.w);
    reinterpret_cast<short4*>(vb)[i] = s;
  }
}

// k transpose: src f32 [B][D][S] -> dst bf16 [B][H][S][64]
__global__ __launch_bounds__(256) void transposek_kernel(const float* __restrict__ src,
                                                         short* __restrict__ dst) {
  __shared__ short t[64][68];
  const int s0 = blockIdx.x * 64, h = blockIdx.y, b = blockIdx.z;
  const int tid = threadIdx.x;
  const float* sp = src + ((size_t)b * D_ + h * DH_) * (size_t)SK_ + s0;
  const int sg = (tid & 15) * 4;
  int dloc = tid >> 4;
  for (int it = 0; it < 4; ++it, dloc += 16) {
    const float4 f = *reinterpret_cast<const float4*>(sp + (size_t)dloc * SK_ + sg);
    t[sg + 0][dloc] = f2bf(f.x);
    t[sg + 1][dloc] = f2bf(f.y);
    t[sg + 2][dloc] = f2bf(f.z);
    t[sg + 3][dloc] = f2bf(f.w);
  }
  __syncthreads();
  short* dp = dst + ((size_t)(b * H_ + h) * SQ_ + s0) * 64;
  for (int it = 0; it < 4; ++it) {
    const int c = tid + 256 * it;
    const int ss = c >> 4, pos = (c & 15) * 4;
    *reinterpret_cast<short4*>(dp + (size_t)ss * 64 + pos) =
        *reinterpret_cast<const short4*>(&t[ss][pos]);
  }
}

// Swapped-operand 32x32 flash attention, fixed-max softmax (P = exp2(s-24)).
// ONE block per (b,h): 16 waves / 1024 threads, wave w owns q-rows [32w,32w+32).
// Grid = 256 = 1 block/CU (single generation, no tail, 4 waves/SIMD).
// K/V staged once per block: per tile, waves 0-7 stage K chunk w, waves 8-15
// stage V chunk w-8 — exactly one gload16 per wave per tile; 3-buffer ring,
// 2 tiles in flight, counted s_waitcnt vmcnt(1) + raw s_barrier (T4).
__global__ __launch_bounds__(1024) void attn_kernel(
    const float* __restrict__ qf32,     // [B][D][SQ] f32
    short* __restrict__ xqT,            // out x: [B][H][SQ][64] bf16
    const short* __restrict__ kT,       // [B][H][SK][64] bf16
    const short* __restrict__ vb,       // [B][D][SK] bf16
    const float* __restrict__ gamma, const float* __restrict__ beta,
    const float* __restrict__ m_qk, const float* __restrict__ s_qk,
    const float2* __restrict__ msv, const float* __restrict__ kbias)
{
  __shared__ float bias_s[SK_];
  __shared__ short kbuf[3][4096];       // 64 rows x 64 shorts, swizzled image
  __shared__ short vbuf[3][4096];

  const int bid = blockIdx.x;           // 0..255 = (b,h)
  const int h = bid & 7, b = bid >> 3;

  const int tid = threadIdx.x, w = tid >> 6, l = tid & 63;
  const int l31 = l & 31, hi = l >> 5;
  const int swz = l31 & 7;

  const float gh = gamma[h], be = beta[h], mq = m_qk[h], sq = s_qk[h];
  const float a2 = gh / (sq * 8.0f) * LOG2E_;
  const float c2 = (be - mq * gh / sq) * LOG2E_ - FIXED_MAX_;

  const size_t bh = (size_t)(b * H_ + h);
  const int qidx = w * 32 + l31;
  const short* kbase = kT + bh * SK_ * 64;
  const short* vbase = vb + ((size_t)b * D_ + h * DH_) * (size_t)SK_;
  const float* qsrc = qf32 + ((size_t)b * D_ + h * DH_) * (size_t)SQ_ + qidx;

  // bias row to LDS (consumed/drained before the staging vmcnt discipline)
  if (tid < 128) {
    floatx4 t = reinterpret_cast<const floatx4*>(kbias + (size_t)b * SK_)[tid];
    t += c2;                             // fold affine offset + fixed max
    reinterpret_cast<floatx4*>(bias_s)[tid] = t;
  }

  // Q fragments (B-operand) direct from f32 (fully consumed -> vmcnt drained)
  short8 qf[4];
  for (int st = 0; st < 4; ++st) {
    float fv[8];
    for (int j = 0; j < 8; ++j)
      fv[j] = qsrc[(size_t)(st * 16 + hi * 8 + j) * SQ_];
    union { uint32_t u[4]; short8 s; } qk;
    for (int j2 = 0; j2 < 4; ++j2)
      qk.u[j2] = cvt_pk_bf16(fv[2 * j2], fv[2 * j2 + 1]);
    qf[st] = qk.s;
  }

  // staging geometry: one 1KB chunk (8 rows x 128B) per wave per tile
  const int rsub = l >> 3;              // 0..7: row within chunk
  const int c16s = (l & 7) ^ rsub;      // swizzled 16B col in source
  const int ck = w & 7;                 // chunk index

  auto stage = [&](int bufi, int it) {
    const int k0 = it * 64;
    if (w < 8)
      gload16(kbase + (size_t)(k0 + ck * 8 + rsub) * 64 + c16s * 8,
              &kbuf[bufi][ck * 512]);
    else
      gload16(vbase + (size_t)(ck * 8 + rsub) * SK_ + k0 + c16s * 8,
              &vbuf[bufi][ck * 512]);
  };

  stage(0, 0);
  stage(1, 1);

  floatx16 oacc[2];
  for (int i = 0; i < 16; ++i) { oacc[0][i] = 0.f; oacc[1][i] = 0.f; }
  float lpart = 0.f;

  // prologue: tile0 landed (own tile1 load stays in flight), bias visible
  asm volatile("s_waitcnt vmcnt(1) lgkmcnt(0)" ::: "memory");
  __builtin_amdgcn_s_barrier();
  __builtin_amdgcn_sched_barrier(0);

  int bc = 0;                            // buffer holding tile `it`
  for (int it = 0; it < 8; ++it) {
    if (it < 6) {
      const int bs = bc >= 1 ? bc - 1 : bc + 2;   // (bc+2)%3: consumed 2 iters ago
      stage(bs, it + 2);
    }

    const int k0 = it * 64;
    const short* kl = kbuf[bc];
    const short* vl = vbuf[bc];

    // ---- S^T = K Q (fragments from swizzled LDS) ----
    floatx16 s0, s1;
    for (int i = 0; i < 16; ++i) { s0[i] = 0.f; s1[i] = 0.f; }
    __builtin_amdgcn_s_setprio(1);
    for (int st = 0; st < 4; ++st) {
      const short8 ka = *reinterpret_cast<const short8*>(
          &kl[(size_t)l31 * 64 + (((st << 1) | hi) ^ swz) * 8]);
      s0 = __builtin_amdgcn_mfma_f32_32x32x16_bf16(ka, qf[st], s0, 0, 0, 0);
    }
    for (int st = 0; st < 4; ++st) {
      const short8 kb = *reinterpret_cast<const short8*>(
          &kl[(size_t)(32 + l31) * 64 + (((st << 1) | hi) ^ swz) * 8]);
      s1 = __builtin_amdgcn_mfma_f32_32x32x16_bf16(kb, qf[st], s1, 0, 0, 0);
    }
    __builtin_amdgcn_s_setprio(0);

    // P = exp2(s*a2 + bias) — raw v_exp_f32; masked: exp2(-1.4e9) = 0 exactly
    float p[32];
    for (int sub = 0; sub < 2; ++sub)
      for (int gg = 0; gg < 4; ++gg) {
        const floatx4 bv = *reinterpret_cast<const floatx4*>(
            &bias_s[k0 + sub * 32 + gg * 8 + hi * 4]);
        for (int r = 0; r < 4; ++r) {
          const float sc = sub ? s1[gg * 4 + r] : s0[gg * 4 + r];
          p[sub * 16 + gg * 4 + r] =
              __builtin_amdgcn_exp2f(__builtin_fmaf(sc, a2, bv[r]));
        }
      }

    // partial row-sum (lane-local; cross-lane deferred to end)
    {
      float a16[16];
      for (int i = 0; i < 16; ++i) a16[i] = p[i] + p[i + 16];
      float a8[8];
      for (int i = 0; i < 8; ++i) a8[i] = a16[i] + a16[i + 8];
      lpart += ((a8[0] + a8[4]) + (a8[1] + a8[5])) + ((a8[2] + a8[6]) + (a8[3] + a8[7]));
    }

    // P -> bf16 words; word j holds (k=2j, k=2j+1) of this lane's k-set
    uint32_t Wd[16];
    for (int j = 0; j < 16; ++j) Wd[j] = cvt_pk_bf16(p[2 * j], p[2 * j + 1]);

    // PV: O^T[d][q] += V[d][k] * P[k][q]; cross-half exchange via permlane32_swap
    __builtin_amdgcn_s_setprio(1);
    for (int kc = 0; kc < 4; ++kc) {
      const int base = (kc >> 1) * 8 + (kc & 1) * 4;
      uint32_t x0 = Wd[base + 0], x1 = Wd[base + 1];
      uint32_t y0 = Wd[base + 2], y1 = Wd[base + 3];
      plane32_swap(x0, y0);
      plane32_swap(x1, y1);
      union { uint32_t u[4]; short8 s; } pk;
      pk.u[0] = x0; pk.u[1] = x1; pk.u[2] = y0; pk.u[3] = y1;
      const short8 pb = pk.s;
      const short8 va0 = *reinterpret_cast<const short8*>(
          &vl[(size_t)l31 * 64 + (((kc << 1) | hi) ^ swz) * 8]);
      const short8 va1 = *reinterpret_cast<const short8*>(
          &vl[(size_t)(32 + l31) * 64 + (((kc << 1) | hi) ^ swz) * 8]);
      oacc[0] = __builtin_amdgcn_mfma_f32_32x32x16_bf16(va0, pb, oacc[0], 0, 0, 0);
      oacc[1] = __builtin_amdgcn_mfma_f32_32x32x16_bf16(va1, pb, oacc[1], 0, 0, 0);
    }
    __builtin_amdgcn_s_setprio(0);

    // counted-vmcnt barrier: tile it+1 landed; own tile it+2 load stays in flight
    if (it < 7) {
      if (it < 6) asm volatile("s_waitcnt vmcnt(1)" ::: "memory");
      else        asm volatile("s_waitcnt vmcnt(0)" ::: "memory");
      __builtin_amdgcn_s_barrier();
      __builtin_amdgcn_sched_barrier(0);
    }
    bc = bc == 2 ? 0 : bc + 1;
  }

  lpart += __shfl_xor(lpart, 32, 64);    // complete row sum

  // ---- epilogue: x = (q + O/l)*inv_s - m*inv_s; residual q re-read f32 (L2-hot) ----
  const float invl = __builtin_amdgcn_rcpf(lpart);
  short* xr = xqT + (bh * SQ_ + qidx) * 64;
  const float2* msvh = msv + h * DH_;
  for (int dt = 0; dt < 2; ++dt)
    for (int gg = 0; gg < 4; ++gg) {
      const int d0 = dt * 32 + gg * 8 + hi * 4;
      float qv[4];
      for (int r = 0; r < 4; ++r) qv[r] = qsrc[(size_t)(d0 + r) * SQ_];
      const float2 c0 = msvh[d0 + 0], c1 = msvh[d0 + 1],
                   c2v = msvh[d0 + 2], c3 = msvh[d0 + 3];
      short4 xv;
      xv.x = f2bf((qv[0] + oacc[dt][gg * 4 + 0] * invl) * c0.x - c0.y);
      xv.y = f2bf((qv[1] + oacc[dt][gg * 4 + 1] * invl) * c1.x - c1.y);
      xv.z = f2bf((qv[2] + oacc[dt][gg * 4 + 2] * invl) * c2v.x - c2v.y);
      xv.w = f2bf((qv[3] + oacc[dt][gg * 4 + 3] * invl) * c3.x - c3.y);
      *reinterpret_cast<short4*>(xr + d0) = xv;
    }
}

// proj: out[b,o,q] = silu(bias[o] + sum_d W[o,d] x[b,q,d]); x layout [b][h][q][64].
__global__ __launch_bounds__(256) void proj_kernel(
    const short* __restrict__ Wb, const short* __restrict__ xT,
    const float* __restrict__ bias, float* __restrict__ out)
{
  __shared__ short xs[64 * 512];        // [row=q][c16, swizzled], 64 KB
  const int q0 = blockIdx.x * 64;
  const int o0 = blockIdx.y * 256;
  const int b  = blockIdx.z;
  const int tid = threadIdx.x, w = tid >> 6, l = tid & 63;
  const int l15 = l & 15, g = l >> 4;

  const short* xb = xT + (size_t)b * (H_ * SQ_ * 64);
  for (int hh = w * 2; hh < w * 2 + 2; ++hh) {
    const short* src = xb + ((size_t)hh * SQ_ + q0) * 64;
    for (int j = 0; j < 8; ++j) {
      const short8 val = *reinterpret_cast<const short8*>(src + j * 512 + l * 8);
      const int row = j * 8 + (l >> 3);
      const int c16 = (hh * 8 + (l & 7)) ^ (row & 7);
      *reinterpret_cast<short8*>(&xs[row * 512 + c16 * 8]) = val;
    }
  }
  __syncthreads();

  floatx4 acc[4][4];
  for (int ai = 0; ai < 4; ++ai)
    for (int bj = 0; bj < 4; ++bj)
      acc[ai][bj] = floatx4{0.f, 0.f, 0.f, 0.f};

  const short* wbase = Wb + (size_t)(o0 + w * 64 + l15) * D_;

  for (int step = 0; step < 16; ++step) {
    short8 af[4];
    for (int ai = 0; ai < 4; ++ai)
      af[ai] = *reinterpret_cast<const short8*>(
          wbase + (size_t)(ai * 16) * D_ + step * 32 + g * 8);
    short8 bf[4];
    for (int bj = 0; bj < 4; ++bj) {
      const int row = bj * 16 + l15;
      const int c16 = (step * 4 + g) ^ (row & 7);
      bf[bj] = *reinterpret_cast<const short8*>(&xs[row * 512 + c16 * 8]);
    }
    for (int ai = 0; ai < 4; ++ai)
      for (int bj = 0; bj < 4; ++bj)
        acc[ai][bj] = __builtin_amdgcn_mfma_f32_16x16x32_bf16(af[ai], bf[bj],
                                                              acc[ai][bj], 0, 0, 0);
  }

  for (int ai = 0; ai < 4; ++ai)
    for (int r = 0; r < 4; ++r) {
      const int o = o0 + w * 64 + ai * 16 + g * 4 + r;
      const float bo = bias[o];
      float* orow = out + ((size_t)b * D_ + o) * SQ_ + q0;
      for (int bj = 0; bj < 4; ++bj) {
        const float val = acc[ai][bj][r] + bo;
        orow[bj * 16 + l15] =
            val * __builtin_amdgcn_rcpf(1.0f + __expf(-val));
      }
    }
}

extern "C" void kernel_launch(void* const* d_in, const int* in_sizes, int n_in,
                              void* d_out, int out_size, void* d_ws, size_t ws_size,
                              hipStream_t stream) {
  const float*   q     = (const float*)d_in[0];
  const float*   k     = (const float*)d_in[1];
  const float*   v     = (const float*)d_in[2];
  const uint8_t* mask  = (const uint8_t*)d_in[3];
  const float*   gamma = (const float*)d_in[4];
  const float*   beta  = (const float*)d_in[5];
  const float*   m_qk  = (const float*)d_in[6];
  const float*   s_qk  = (const float*)d_in[7];
  const float*   m_v   = (const float*)d_in[8];
  const float*   s_v   = (const float*)d_in[9];
  const float*   W     = (const float*)d_in[10];
  const float*   bias  = (const float*)d_in[11];
  float* out = (float*)d_out;

  char* ws = (char*)d_ws;
  short*  Wb    = (short*)ws;                                   // 512 KB
  short*  xqT   = (short*)(ws + (1u << 19));                    // 16 MB (x output)
  short*  kTb   = (short*)(ws + (1u << 19) + (1u << 24));       // 16 MB
  short*  vbb   = (short*)(ws + (1u << 19) + 2u * (1u << 24));  // 16 MB
  float2* msv   = (float2*)(ws + (1u << 19) + 3u * (1u << 24)); // 4 KB
  int*    flag  = (int*)(ws + (1u << 19) + 3u * (1u << 24) + 4096);
  float*  kbias = (float*)(ws + (1u << 19) + 3u * (1u << 24) + 8192); // 64 KB

  detect_mask_kernel<<<1, 256, 0, stream>>>(mask, flag);
  prep_kernel<<<161, 512, 0, stream>>>(mask, flag, kbias, m_v, s_v, msv, W, Wb);
  transposek_kernel<<<dim3(8, 8, 32), 256, 0, stream>>>(k, kTb);
  convv_kernel<<<2048, 256, 0, stream>>>(v, vbb);
  attn_kernel<<<256, 1024, 0, stream>>>(q, xqT, kTb, vbb, gamma, beta,
                                        m_qk, s_qk, msv, kbias);
  proj_kernel<<<dim3(8, 2, 32), 256, 0, stream>>>(Wb, xqT, bias, out);
}